// Round 7
// baseline (610.672 us; speedup 1.0000x reference)
//
#include <hip/hip_runtime.h>
#include <math.h>

// 2 iterations of {row-L2-normalize -> scatter-add over 32M edges -> 2x2 matmul
// + ReLU}, then sigmoid(x @ final_weight). N = 1M nodes, E = 32M edges.
//
// Spec path (device-verified: W col1 == -col0 both iters): iter1 aggregates
// g[src] (1 f32 LDS atomic/edge), classes written directly in agg epilogue;
// iter2 aggregates packed P<<16|Q class counts (1 u32 LDS atomic/edge).
// R6 lesson: agg scales with waves/CU x per-wave MLP (not BW, not LDS-lane
// throughput alone). R7: 16-deep gather unroll in agg; bin at 32 waves/CU
// (CHUNK 8192, ~57 KB LDS); cls_k fused into agg_s<0>.

#define EPS 1e-15f
#define SB_BITS 11
#define SB 2048              // dst nodes per bucket (489 agg blocks, 2/CU)
#define NBW 1024             // padded key width (real nbk = 489*2 = 978)
#define CHUNK 8192           // edges per partition block
#define BIN_T 1024
#define SCAN_BK 8
#define UNR 16               // agg edges per thread per pass

typedef unsigned int u32;
typedef unsigned short u16;
typedef unsigned char u8;
typedef unsigned int u32x4 __attribute__((ext_vector_type(4)));

// ---------------- flag: does W have the col1 == -col0 property? ----------------

__global__ void flag_k(const float* __restrict__ W, u32* __restrict__ flag) {
    bool ok = (W[1] == -W[0]) && (W[3] == -W[2]) &&
              (W[5] == -W[4]) && (W[7] == -W[6]);
    *flag = ok ? 1u : 0u;
}

// ---------------- node-wise kernels ----------------

// spec: g[n] = (w00*x.x + w10*x.y) / (|x| + eps)
__global__ void g_k(const float2* __restrict__ x, const float* __restrict__ W,
                    float* __restrict__ g, int N, const u32* __restrict__ flag) {
    if (*flag != 1u) return;
    int n = blockIdx.x * blockDim.x + threadIdx.x;
    if (n >= N) return;
    float2 v = x[n];
    float nm = sqrtf(v.x * v.x + v.y * v.y);
    float inv = 1.0f / (nm + EPS);
    g[n] = (W[0] * v.x + W[2] * v.y) * inv;
}

// general/fallback: normalize x into A (want: -1 = always, else require *flag==want)
__global__ void norm_input_kernel(const float2* __restrict__ x,
                                  float2* __restrict__ A, int N,
                                  const u32* __restrict__ flag, int want) {
    if (want >= 0 && *flag != (u32)want) return;
    int n = blockIdx.x * blockDim.x + threadIdx.x;
    if (n >= N) return;
    float2 v = x[n];
    float nm = sqrtf(v.x * v.x + v.y * v.y);
    float inv = 1.0f / (nm + EPS);
    A[n] = make_float2(v.x * inv, v.y * inv);
}

// spec: out = sigmoid(f0*relu(u2) + f1*relu(-u2)), u2 = w00'*P + w10'*Q
__global__ void final_s_k(const u32* __restrict__ cnt, float* __restrict__ out,
                          const float* __restrict__ W, const float* __restrict__ fw,
                          int N, const u32* __restrict__ flag) {
    if (*flag != 1u) return;
    int n = blockIdx.x * blockDim.x + threadIdx.x;
    if (n >= N) return;
    u32 c = cnt[n];
    float P = (float)(c >> 16), Q = (float)(c & 0xFFFFu);
    float u2 = W[4] * P + W[6] * Q;
    float z = fw[0] * fmaxf(u2, 0.0f) + fw[1] * fmaxf(-u2, 0.0f);
    out[n] = 1.0f / (1.0f + expf(-z));
}

// general/fallback: A = normalize(relu(B @ W))
__global__ void wrelu_norm_kernel(const float2* __restrict__ B,
                                  float2* __restrict__ A,
                                  const float* __restrict__ W, int N,
                                  const u32* __restrict__ flag, int want) {
    if (want >= 0 && *flag != (u32)want) return;
    int n = blockIdx.x * blockDim.x + threadIdx.x;
    if (n >= N) return;
    float w00 = W[0], w01 = W[1], w10 = W[2], w11 = W[3];
    float2 b = B[n];
    float y0 = fmaxf(b.x * w00 + b.y * w10, 0.0f);
    float y1 = fmaxf(b.x * w01 + b.y * w11, 0.0f);
    float nm = sqrtf(y0 * y0 + y1 * y1);
    float inv = 1.0f / (nm + EPS);
    A[n] = make_float2(y0 * inv, y1 * inv);
}

// general/fallback: out = sigmoid(relu(B @ W) . fw)
__global__ void wrelu_sig_kernel(const float2* __restrict__ B,
                                 float* __restrict__ out,
                                 const float* __restrict__ W,
                                 const float* __restrict__ fw, int N,
                                 const u32* __restrict__ flag, int want) {
    if (want >= 0 && *flag != (u32)want) return;
    int n = blockIdx.x * blockDim.x + threadIdx.x;
    if (n >= N) return;
    float w00 = W[0], w01 = W[1], w10 = W[2], w11 = W[3];
    float f0 = fw[0], f1 = fw[1];
    float2 b = B[n];
    float y0 = fmaxf(b.x * w00 + b.y * w10, 0.0f);
    float y1 = fmaxf(b.x * w01 + b.y * w11, 0.0f);
    float z = y0 * f0 + y1 * f1;
    out[n] = 1.0f / (1.0f + expf(-z));
}

// ---------------- partition pipeline (flag-independent) ----------------

// P0: per-(block,key) histogram, block-major H[blk][key]; key = bucket*2 | slice
__global__ __launch_bounds__(BIN_T) void hist_k(const int* __restrict__ src,
                                                const int* __restrict__ dst,
                                                int E, int sliceShift,
                                                u16* __restrict__ H) {
    __shared__ u32 h[NBW];
    int t = threadIdx.x;
    h[t] = 0;
    __syncthreads();
    int e0 = blockIdx.x * CHUNK, e1 = min(E, e0 + CHUNK);
    for (int e = e0 + t; e < e1; e += BIN_T) {
        int key = ((dst[e] >> SB_BITS) << 1) | (src[e] >> sliceShift);
        atomicAdd(&h[key], 1u);
    }
    __syncthreads();
    H[(size_t)blockIdx.x * NBW + t] = (u16)h[t];
}

// P1: in-place exclusive scan of H along blocks, per key; totals -> T
__global__ void colscan_k(u16* __restrict__ H, int gridC, u32* __restrict__ T) {
    __shared__ u32 tile[SCAN_BK][257];
    __shared__ u32 carry[SCAN_BK];
    int t = threadIdx.x;                // 256
    int b0 = blockIdx.x * SCAN_BK;
    if (t < SCAN_BK) carry[t] = 0;
    __syncthreads();
    int w = t >> 6, lane = t & 63;
    int rounds = (gridC + 255) / 256;
    for (int i = 0; i < rounds; ++i) {
        int blk = i * 256 + t;
        u32 vals[SCAN_BK];
        #pragma unroll
        for (int j = 0; j < SCAN_BK; ++j) vals[j] = 0;
        if (blk < gridC) {
            const u16* p = H + (size_t)blk * NBW + b0;
            uint4 v = *(const uint4*)p;     // 8 x u16
            vals[0] = v.x & 0xFFFFu; vals[1] = v.x >> 16;
            vals[2] = v.y & 0xFFFFu; vals[3] = v.y >> 16;
            vals[4] = v.z & 0xFFFFu; vals[5] = v.z >> 16;
            vals[6] = v.w & 0xFFFFu; vals[7] = v.w >> 16;
        }
        #pragma unroll
        for (int j = 0; j < SCAN_BK; ++j) tile[j][t] = vals[j];
        __syncthreads();
        for (int c = w * 2; c < w * 2 + 2; ++c) {
            u32 cb = carry[c];
            u32 run = 0;
            for (int seg = 0; seg < 4; ++seg) {
                u32 x = tile[c][seg * 64 + lane];
                u32 inc = x;
                for (int off = 1; off < 64; off <<= 1) {
                    u32 y = __shfl_up(inc, off);
                    if (lane >= off) inc += y;
                }
                tile[c][seg * 64 + lane] = inc - x + run + cb;
                run += __shfl(inc, 63);
            }
            if (lane == 0) carry[c] = cb + run;
        }
        __syncthreads();
        if (blk < gridC) {
            #pragma unroll
            for (int j = 0; j < SCAN_BK; ++j) vals[j] = tile[j][t];
            u16* p = H + (size_t)blk * NBW + b0;
            uint4 v;
            v.x = vals[0] | (vals[1] << 16);
            v.y = vals[2] | (vals[3] << 16);
            v.z = vals[4] | (vals[5] << 16);
            v.w = vals[6] | (vals[7] << 16);
            *(uint4*)p = v;
        }
        __syncthreads();
    }
    if (t < SCAN_BK) T[b0 + t] = carry[t];
}

// P2: key bases, rounded to 4 words (16B) for vectorized agg loads
__global__ __launch_bounds__(512) void base_k(const u32* __restrict__ T,
                                              u32* __restrict__ base) {
    __shared__ u32 wp[8];
    int t = threadIdx.x;                // 512, VPT = 2
    u32 loc[2];
    u32 s = 0;
    for (int j = 0; j < 2; ++j) {
        loc[j] = (T[t * 2 + j] + 3u) & ~3u;
        s += loc[j];
    }
    int lane = t & 63, w = t >> 6;
    u32 inc = s;
    for (int off = 1; off < 64; off <<= 1) {
        u32 y = __shfl_up(inc, off);
        if (lane >= off) inc += y;
    }
    if (lane == 63) wp[w] = inc;
    __syncthreads();
    u32 add = 0;
    for (int j = 0; j < w; ++j) add += wp[j];
    u32 run = inc - s + add;
    for (int j = 0; j < 2; ++j) {
        base[t * 2 + j] = run;
        run += loc[j];
    }
    if (t == 511) base[NBW] = run;
}

// P3: block-local key sort in LDS, then coalesced run flush (~57 KB LDS -> 2/CU)
__global__ __launch_bounds__(BIN_T) void bin_k(const int* __restrict__ src,
                                               const int* __restrict__ dst,
                                               int E, int sliceShift,
                                               const u16* __restrict__ H,
                                               const u32* __restrict__ base,
                                               u32* __restrict__ bucketed) {
    __shared__ u32 h[NBW];               // counts, then D = base + Hrow - start
    __shared__ u32 cur[NBW];
    __shared__ u32 stage[CHUNK];         // 32 KB
    __shared__ u16 kk[CHUNK];            // 16 KB
    __shared__ u32 wp[16];
    int t = threadIdx.x;                 // 1024
    int e0 = blockIdx.x * CHUNK, e1 = min(E, e0 + CHUNK), n = e1 - e0;
    h[t] = 0;
    __syncthreads();
    for (int e = e0 + t; e < e1; e += BIN_T) {
        int key = ((dst[e] >> SB_BITS) << 1) | (src[e] >> sliceShift);
        atomicAdd(&h[key], 1u);
    }
    __syncthreads();
    // exclusive scan h -> start (1 key per thread)
    u32 v = h[t];
    int lane = t & 63, w = t >> 6;
    u32 inc = v;
    for (int off = 1; off < 64; off <<= 1) {
        u32 y = __shfl_up(inc, off);
        if (lane >= off) inc += y;
    }
    if (lane == 63) wp[w] = inc;
    __syncthreads();
    u32 add = 0;
    for (int j = 0; j < w; ++j) add += wp[j];
    u32 start = inc - v + add;
    cur[t] = start;
    h[t] = base[t] + (u32)H[(size_t)blockIdx.x * NBW + t] - start;  // D (mod 2^32)
    __syncthreads();
    // rank + stage (key-sorted within block)
    for (int e = e0 + t; e < e1; e += BIN_T) {
        int d = dst[e];
        int sc = src[e];
        int key = ((d >> SB_BITS) << 1) | (sc >> sliceShift);
        u32 r = atomicAdd(&cur[key], 1u);
        stage[r] = ((u32)(d & (SB - 1)) << 20) | (u32)sc;
        kk[r] = (u16)key;
    }
    __syncthreads();
    // flush: consecutive i -> consecutive global positions within runs
    for (int i = t; i < n; i += BIN_T)
        bucketed[h[kk[i]] + (u32)i] = stage[i];
}

// ---------------- aggregation (spec) ----------------

// KIND 0: f32 g-table -> u8 class output (cls fused into epilogue)
// KIND 1: u8 class table -> packed P<<16|Q u32 counts
template <int KIND>
__global__ __launch_bounds__(1024) void agg_s(
        const u32* __restrict__ bucketed, const u32* __restrict__ base,
        const u32* __restrict__ T, const void* __restrict__ tab,
        void* __restrict__ outp, int N, const u32* __restrict__ flag) {
    if (*flag != 1u) return;
    __shared__ u32 acc[SB];              // 8 KB
    int b = blockIdx.x, t = threadIdx.x;
    acc[t] = 0u;
    acc[t + 1024] = 0u;
    __syncthreads();
    const float* gt = (const float*)tab;
    const u8* ct = (const u8*)tab;
    #pragma unroll
    for (int sl = 0; sl < 2; ++sl) {
        int k = b * 2 + sl;
        u32 p0 = base[k], cnt = T[k];
        for (u32 q = (u32)UNR * (u32)t; q < cnt; q += 1024u * UNR) {
            const u32x4* p = (const u32x4*)(bucketed + p0 + q);
            u32 wv[UNR];
            #pragma unroll
            for (int j4 = 0; j4 < UNR / 4; ++j4) {
                u32x4 wq = __builtin_nontemporal_load(p + j4);
                wv[4 * j4 + 0] = wq[0]; wv[4 * j4 + 1] = wq[1];
                wv[4 * j4 + 2] = wq[2]; wv[4 * j4 + 3] = wq[3];
            }
            if (KIND == 0) {
                float gv[UNR];
                #pragma unroll
                for (int j = 0; j < UNR; ++j) {
                    u32 s = wv[j] & 0xFFFFFu;
                    s = min(s, (u32)(N - 1));
                    gv[j] = gt[s];               // 16 independent gathers
                }
                #pragma unroll
                for (int j = 0; j < UNR; ++j)
                    if (q + j < cnt)
                        atomicAdd((float*)&acc[wv[j] >> 20], gv[j]);
            } else {
                u32 av[UNR];
                #pragma unroll
                for (int j = 0; j < UNR; ++j) {
                    u32 s = wv[j] & 0xFFFFFu;
                    s = min(s, (u32)(N - 1));
                    u8 c = ct[s];
                    av[j] = (c == (u8)1) ? 65536u : ((c == (u8)2) ? 1u : 0u);
                }
                #pragma unroll
                for (int j = 0; j < UNR; ++j)
                    if (q + j < cnt)
                        atomicAdd(&acc[wv[j] >> 20], av[j]);
            }
        }
    }
    __syncthreads();
    int n0 = b << SB_BITS;
    if (KIND == 0) {
        u8* cls = (u8*)outp;
        for (int i = t; i < SB && n0 + i < N; i += 1024) {
            float u = __uint_as_float(acc[i]);
            cls[n0 + i] = (u > 0.0f) ? (u8)1 : ((u < 0.0f) ? (u8)2 : (u8)0);
        }
    } else {
        u32* cnt = (u32*)outp;
        for (int i = t; i < SB && n0 + i < N; i += 1024) cnt[n0 + i] = acc[i];
    }
}

// general: float2 table -> float2 B (2 f32 LDS atomics/edge)
__global__ __launch_bounds__(1024) void agg_g(
        const u32* __restrict__ bucketed, const u32* __restrict__ base,
        const u32* __restrict__ T, const float2* __restrict__ A,
        float2* __restrict__ B, int N, const u32* __restrict__ flag) {
    if (*flag != 0u) return;
    __shared__ float acc[SB * 2];        // 16 KB
    int b = blockIdx.x, t = threadIdx.x;
    for (int i = t; i < SB * 2; i += 1024) acc[i] = 0.0f;
    __syncthreads();
    #pragma unroll
    for (int sl = 0; sl < 2; ++sl) {
        int k = b * 2 + sl;
        u32 p0 = base[k], cnt = T[k];
        for (u32 q = 8u * (u32)t; q < cnt; q += 8192u) {
            const u32x4* p = (const u32x4*)(bucketed + p0 + q);
            u32x4 wa = __builtin_nontemporal_load(p);
            u32x4 wb = __builtin_nontemporal_load(p + 1);
            u32 wv[8] = {wa[0], wa[1], wa[2], wa[3], wb[0], wb[1], wb[2], wb[3]};
            float2 vv[8];
            #pragma unroll
            for (int j = 0; j < 8; ++j) {
                u32 s = wv[j] & 0xFFFFFu;
                s = min(s, (u32)(N - 1));
                vv[j] = A[s];
            }
            #pragma unroll
            for (int j = 0; j < 8; ++j) {
                if (q + j < cnt) {
                    int dl = (int)(wv[j] >> 20);
                    atomicAdd(&acc[2 * dl], vv[j].x);
                    atomicAdd(&acc[2 * dl + 1], vv[j].y);
                }
            }
        }
    }
    __syncthreads();
    int n0 = b << SB_BITS;
    for (int i = t; i < SB && n0 + i < N; i += 1024)
        B[n0 + i] = make_float2(acc[2 * i], acc[2 * i + 1]);
}

// ---------------- fallback: direct global-atomic scatter ----------------

__global__ void scatter_kernel(const int* __restrict__ src,
                               const int* __restrict__ dst,
                               const float2* __restrict__ A,
                               float* __restrict__ B, int E) {
    int tid = blockIdx.x * blockDim.x + threadIdx.x;
    int stride = gridDim.x * blockDim.x;
    for (int e = tid; e < E; e += stride) {
        int s = src[e];
        int d = dst[e];
        float2 v = A[s];
        atomicAdd(&B[2 * d], v.x);
        atomicAdd(&B[2 * d + 1], v.y);
    }
}

extern "C" void kernel_launch(void* const* d_in, const int* in_sizes, int n_in,
                              void* d_out, int out_size, void* d_ws, size_t ws_size,
                              hipStream_t stream) {
    const float* x = (const float*)d_in[0];          // [N,2]
    const int* edge_index = (const int*)d_in[1];     // [2,E]
    const float* W = (const float*)d_in[2];          // [2,2,2]
    const float* fw = (const float*)d_in[3];         // [2]
    float* out = (float*)d_out;                      // [N]

    const int N = in_sizes[0] / 2;
    const int E = in_sizes[1] / 2;
    const int* src = edge_index;       // row 0 = message source j
    const int* dst = edge_index + E;   // row 1 = aggregation target i

    const int NB = (N + SB - 1) >> SB_BITS;          // 489
    const int gridC = (E + CHUNK - 1) / CHUNK;       // 3907
    int nbits = 1;
    while ((1 << nbits) < N) ++nbits;                // 20
    const int sliceShift = nbits - 1;                // 2 src slices

    // workspace layout:
    //  U1 [0, 8MB): spec: g f32[N] @0, cls u8[N] @4MB | general: A0 float2[N]
    //  U2 [8MB, +max(H, B, cnt)): H u16[gridC*NBW] (dead before agg writes)
    //        spec: cnt u32[N] @+0 | general: B float2[N]
    //  bucketed u32[E + CHUNK] | T u32[NBW] | base u32[NBW+1] | flag u32
    char* ws = (char*)d_ws;
    size_t aBytes = (size_t)N * 2 * sizeof(float);           // 8 MB
    size_t hBytes = (size_t)gridC * NBW * sizeof(u16);       // ~8 MB
    size_t bBytes = (size_t)N * 2 * sizeof(float);           // 8 MB
    size_t uBytes = (hBytes > bBytes ? hBytes : bBytes);

    float* g    = (float*)ws;
    u8*   cls   = (u8*)(ws + (size_t)N * sizeof(float));
    float2* A0  = (float2*)ws;
    u16*  H     = (u16*)(ws + aBytes);
    u32*  cnt   = (u32*)(ws + aBytes);
    float* Bg   = (float*)(ws + aBytes);
    u32* bucketed = (u32*)(ws + aBytes + uBytes);            // [E + CHUNK]
    u32* T    = bucketed + (size_t)E + CHUNK;                // [NBW]
    u32* base = T + NBW;                                     // [NBW+1]
    u32* flag = base + NBW + 1;
    size_t need = (char*)(flag + 1) - ws;

    const int BLK = 256;
    const int gridN = (N + BLK - 1) / BLK;

    flag_k<<<1, 1, 0, stream>>>(W, flag);

    if (ws_size >= need && 2 * NB <= NBW && N <= (1 << 20) && E <= (1 << 25)) {
        // tables (flag-gated; disjoint use of U1)
        g_k<<<gridN, BLK, 0, stream>>>((const float2*)x, W, g, N, flag);
        norm_input_kernel<<<gridN, BLK, 0, stream>>>((const float2*)x, A0, N,
                                                     flag, 0);
        // partition (flag-independent)
        hist_k<<<gridC, BIN_T, 0, stream>>>(src, dst, E, sliceShift, H);
        colscan_k<<<NBW / SCAN_BK, 256, 0, stream>>>(H, gridC, T);
        base_k<<<1, 512, 0, stream>>>(T, base);
        bin_k<<<gridC, BIN_T, 0, stream>>>(src, dst, E, sliceShift, H, base,
                                           bucketed);
        // iter 1 (spec: g -> cls directly; general: A0 -> Bg)
        agg_s<0><<<NB, 1024, 0, stream>>>(bucketed, base, T, g, cls, N, flag);
        agg_g<<<NB, 1024, 0, stream>>>(bucketed, base, T, (const float2*)A0,
                                       (float2*)Bg, N, flag);
        wrelu_norm_kernel<<<gridN, BLK, 0, stream>>>((const float2*)Bg, A0, W,
                                                     N, flag, 0);
        // iter 2
        agg_s<1><<<NB, 1024, 0, stream>>>(bucketed, base, T, cls, cnt, N, flag);
        agg_g<<<NB, 1024, 0, stream>>>(bucketed, base, T, (const float2*)A0,
                                       (float2*)Bg, N, flag);
        final_s_k<<<gridN, BLK, 0, stream>>>(cnt, out, W, fw, N, flag);
        wrelu_sig_kernel<<<gridN, BLK, 0, stream>>>((const float2*)Bg, out,
                                                    W + 4, fw, N, flag, 0);
    } else {
        // fallback: direct atomic scatter (generic, flag-independent)
        float* B = (float*)(ws + aBytes);
        const size_t featBytes = (size_t)N * 2 * sizeof(float);
        const int gridE = 8192;
        norm_input_kernel<<<gridN, BLK, 0, stream>>>((const float2*)x, A0, N,
                                                     flag, -1);
        hipMemsetAsync(B, 0, featBytes, stream);
        scatter_kernel<<<gridE, BLK, 0, stream>>>(src, dst, (const float2*)A0,
                                                  B, E);
        wrelu_norm_kernel<<<gridN, BLK, 0, stream>>>((const float2*)B, A0, W,
                                                     N, flag, -1);
        hipMemsetAsync(B, 0, featBytes, stream);
        scatter_kernel<<<gridE, BLK, 0, stream>>>(src, dst, (const float2*)A0,
                                                  B, E);
        wrelu_sig_kernel<<<gridN, BLK, 0, stream>>>((const float2*)B, out,
                                                    W + 4, fw, N, flag, -1);
    }
}

// Round 8
// 512.248 us; speedup vs baseline: 1.1921x; 1.1921x over previous
//
#include <hip/hip_runtime.h>
#include <math.h>

// 2 iterations of {row-L2-normalize -> scatter-add over 32M edges -> 2x2 matmul
// + ReLU}, then sigmoid(x @ final_weight). N = 1M nodes, E = 32M edges.
//
// Spec path (device-verified: W col1 == -col0 both iters): iter1 aggregates
// g[src] (f32, sign-critical -> L2 gathers, request-rate-bound ~184us floor);
// iter2's gather table is TERNARY -> 2-bit packed (256 KB), sliced 32 KB per
// 128K src nodes and staged in LDS -> gathers become ds_read, ZERO L2 requests.
// Partition key = dst_bucket(4096)*8 + (src>>17): 1960 keys. agg1 splits each
// bucket into dl-halves (490 blocks -> 32 waves/CU). cls 2-bit written in agg1
// epilogue; sigmoid fused into agg2 epilogue. bin uses XCD-contiguous chunk
// swizzle so short runs coalesce in L2.

#define EPS 1e-15f
#define SB_BITS 12
#define SB 4096              // dst nodes per bucket (NB = 245)
#define NBW 2048             // padded key width (real = 245*8 = 1960)
#define CHUNK 8192           // edges per partition block
#define BIN_T 1024
#define SCAN_BK 8

typedef unsigned int u32;
typedef unsigned short u16;
typedef unsigned char u8;
typedef unsigned int u32x4 __attribute__((ext_vector_type(4)));

// XCD-contiguous chunk id: consecutive chunks land on the same XCD
__device__ inline int chunk_id(int bid, int gridC) {
    int q = gridC >> 3, r = gridC & 7;
    int x = bid & 7, i = bid >> 3;
    int base = (x < r) ? x * (q + 1) : r * (q + 1) + (x - r) * q;
    return base + i;
}

// ---------------- flag: does W have the col1 == -col0 property? ----------------

__global__ void flag_k(const float* __restrict__ W, u32* __restrict__ flag) {
    bool ok = (W[1] == -W[0]) && (W[3] == -W[2]) &&
              (W[5] == -W[4]) && (W[7] == -W[6]);
    *flag = ok ? 1u : 0u;
}

// ---------------- node-wise kernels ----------------

// spec: g[n] = (w00*x.x + w10*x.y) / (|x| + eps)
__global__ void g_k(const float2* __restrict__ x, const float* __restrict__ W,
                    float* __restrict__ g, int N, const u32* __restrict__ flag) {
    if (*flag != 1u) return;
    int n = blockIdx.x * blockDim.x + threadIdx.x;
    if (n >= N) return;
    float2 v = x[n];
    float nm = sqrtf(v.x * v.x + v.y * v.y);
    float inv = 1.0f / (nm + EPS);
    g[n] = (W[0] * v.x + W[2] * v.y) * inv;
}

// general/fallback: normalize x into A (want: -1 = always, else require *flag==want)
__global__ void norm_input_kernel(const float2* __restrict__ x,
                                  float2* __restrict__ A, int N,
                                  const u32* __restrict__ flag, int want) {
    if (want >= 0 && *flag != (u32)want) return;
    int n = blockIdx.x * blockDim.x + threadIdx.x;
    if (n >= N) return;
    float2 v = x[n];
    float nm = sqrtf(v.x * v.x + v.y * v.y);
    float inv = 1.0f / (nm + EPS);
    A[n] = make_float2(v.x * inv, v.y * inv);
}

// general/fallback: A = normalize(relu(B @ W))
__global__ void wrelu_norm_kernel(const float2* __restrict__ B,
                                  float2* __restrict__ A,
                                  const float* __restrict__ W, int N,
                                  const u32* __restrict__ flag, int want) {
    if (want >= 0 && *flag != (u32)want) return;
    int n = blockIdx.x * blockDim.x + threadIdx.x;
    if (n >= N) return;
    float w00 = W[0], w01 = W[1], w10 = W[2], w11 = W[3];
    float2 b = B[n];
    float y0 = fmaxf(b.x * w00 + b.y * w10, 0.0f);
    float y1 = fmaxf(b.x * w01 + b.y * w11, 0.0f);
    float nm = sqrtf(y0 * y0 + y1 * y1);
    float inv = 1.0f / (nm + EPS);
    A[n] = make_float2(y0 * inv, y1 * inv);
}

// general/fallback: out = sigmoid(relu(B @ W) . fw)
__global__ void wrelu_sig_kernel(const float2* __restrict__ B,
                                 float* __restrict__ out,
                                 const float* __restrict__ W,
                                 const float* __restrict__ fw, int N,
                                 const u32* __restrict__ flag, int want) {
    if (want >= 0 && *flag != (u32)want) return;
    int n = blockIdx.x * blockDim.x + threadIdx.x;
    if (n >= N) return;
    float w00 = W[0], w01 = W[1], w10 = W[2], w11 = W[3];
    float f0 = fw[0], f1 = fw[1];
    float2 b = B[n];
    float y0 = fmaxf(b.x * w00 + b.y * w10, 0.0f);
    float y1 = fmaxf(b.x * w01 + b.y * w11, 0.0f);
    float z = y0 * f0 + y1 * f1;
    out[n] = 1.0f / (1.0f + expf(-z));
}

// ---------------- partition pipeline (flag-independent) ----------------

// P0: per-(chunk,key) histogram, chunk-major H[cid][key]
__global__ __launch_bounds__(BIN_T) void hist_k(const int* __restrict__ src,
                                                const int* __restrict__ dst,
                                                int E, int gridC,
                                                u16* __restrict__ H) {
    __shared__ u32 h[NBW];
    int t = threadIdx.x;
    h[t] = 0; h[t + 1024] = 0;
    __syncthreads();
    int cid = chunk_id(blockIdx.x, gridC);
    int e0 = cid * CHUNK, e1 = min(E, e0 + CHUNK);
    for (int e = e0 + t; e < e1; e += BIN_T) {
        int key = ((dst[e] >> SB_BITS) << 3) | ((src[e] >> 17) & 7);
        atomicAdd(&h[key], 1u);
    }
    __syncthreads();
    u16* row = H + (size_t)cid * NBW;
    row[t] = (u16)h[t];
    row[t + 1024] = (u16)h[t + 1024];
}

// P1: in-place exclusive scan of H along chunks, per key; totals -> T
__global__ void colscan_k(u16* __restrict__ H, int gridC, u32* __restrict__ T) {
    __shared__ u32 tile[SCAN_BK][257];
    __shared__ u32 carry[SCAN_BK];
    int t = threadIdx.x;                // 256
    int b0 = blockIdx.x * SCAN_BK;
    if (t < SCAN_BK) carry[t] = 0;
    __syncthreads();
    int w = t >> 6, lane = t & 63;
    int rounds = (gridC + 255) / 256;
    for (int i = 0; i < rounds; ++i) {
        int blk = i * 256 + t;
        u32 vals[SCAN_BK];
        #pragma unroll
        for (int j = 0; j < SCAN_BK; ++j) vals[j] = 0;
        if (blk < gridC) {
            const u16* p = H + (size_t)blk * NBW + b0;
            uint4 v = *(const uint4*)p;     // 8 x u16
            vals[0] = v.x & 0xFFFFu; vals[1] = v.x >> 16;
            vals[2] = v.y & 0xFFFFu; vals[3] = v.y >> 16;
            vals[4] = v.z & 0xFFFFu; vals[5] = v.z >> 16;
            vals[6] = v.w & 0xFFFFu; vals[7] = v.w >> 16;
        }
        #pragma unroll
        for (int j = 0; j < SCAN_BK; ++j) tile[j][t] = vals[j];
        __syncthreads();
        for (int c = w * 2; c < w * 2 + 2; ++c) {
            u32 cb = carry[c];
            u32 run = 0;
            for (int seg = 0; seg < 4; ++seg) {
                u32 x = tile[c][seg * 64 + lane];
                u32 inc = x;
                for (int off = 1; off < 64; off <<= 1) {
                    u32 y = __shfl_up(inc, off);
                    if (lane >= off) inc += y;
                }
                tile[c][seg * 64 + lane] = inc - x + run + cb;
                run += __shfl(inc, 63);
            }
            if (lane == 0) carry[c] = cb + run;
        }
        __syncthreads();
        if (blk < gridC) {
            #pragma unroll
            for (int j = 0; j < SCAN_BK; ++j) vals[j] = tile[j][t];
            u16* p = H + (size_t)blk * NBW + b0;
            uint4 v;
            v.x = vals[0] | (vals[1] << 16);
            v.y = vals[2] | (vals[3] << 16);
            v.z = vals[4] | (vals[5] << 16);
            v.w = vals[6] | (vals[7] << 16);
            *(uint4*)p = v;
        }
        __syncthreads();
    }
    if (t < SCAN_BK) T[b0 + t] = carry[t];
}

// P2: key bases, rounded to 4 words (16B) for vectorized agg loads
__global__ __launch_bounds__(512) void base_k(const u32* __restrict__ T,
                                              u32* __restrict__ base) {
    __shared__ u32 wp[8];
    int t = threadIdx.x;                // 512, VPT = 4
    u32 loc[4];
    u32 s = 0;
    #pragma unroll
    for (int j = 0; j < 4; ++j) {
        loc[j] = (T[t * 4 + j] + 3u) & ~3u;
        s += loc[j];
    }
    int lane = t & 63, w = t >> 6;
    u32 inc = s;
    for (int off = 1; off < 64; off <<= 1) {
        u32 y = __shfl_up(inc, off);
        if (lane >= off) inc += y;
    }
    if (lane == 63) wp[w] = inc;
    __syncthreads();
    u32 add = 0;
    for (int j = 0; j < w; ++j) add += wp[j];
    u32 run = inc - s + add;
    #pragma unroll
    for (int j = 0; j < 4; ++j) {
        base[t * 4 + j] = run;
        run += loc[j];
    }
    if (t == 511) base[NBW] = run;
}

// P3: block-local key sort in LDS, then coalesced run flush (~57 KB LDS)
__global__ __launch_bounds__(BIN_T) void bin_k(const int* __restrict__ src,
                                               const int* __restrict__ dst,
                                               int E, int gridC,
                                               const u16* __restrict__ H,
                                               const u32* __restrict__ base,
                                               u32* __restrict__ bucketed) {
    __shared__ u32 h[NBW];               // counts, then D = base + Hrow - start
    __shared__ u32 cur[NBW];
    __shared__ u32 stage[CHUNK];         // 32 KB
    __shared__ u8 sbk[CHUNK];            // 8 KB (dst bucket, < 256)
    __shared__ u32 wp[16];
    int t = threadIdx.x;                 // 1024
    int cid = chunk_id(blockIdx.x, gridC);
    int e0 = cid * CHUNK, e1 = min(E, e0 + CHUNK), n = e1 - e0;
    h[t] = 0; h[t + 1024] = 0;
    __syncthreads();
    for (int e = e0 + t; e < e1; e += BIN_T) {
        int key = ((dst[e] >> SB_BITS) << 3) | ((src[e] >> 17) & 7);
        atomicAdd(&h[key], 1u);
    }
    __syncthreads();
    // exclusive scan h -> start (2 keys per thread)
    u32 loc0 = h[2 * t], loc1 = h[2 * t + 1];
    u32 s = loc0 + loc1;
    int lane = t & 63, w = t >> 6;
    u32 inc = s;
    for (int off = 1; off < 64; off <<= 1) {
        u32 y = __shfl_up(inc, off);
        if (lane >= off) inc += y;
    }
    if (lane == 63) wp[w] = inc;
    __syncthreads();
    u32 add = 0;
    for (int j = 0; j < w; ++j) add += wp[j];
    u32 run = inc - s + add;
    const u16* Hrow = H + (size_t)cid * NBW;
    u32 st0 = run, st1 = run + loc0;
    u32 hr0 = (u32)Hrow[2 * t], hr1 = (u32)Hrow[2 * t + 1];
    __syncthreads();                     // counts consumed before h overwrite
    cur[2 * t] = st0;
    cur[2 * t + 1] = st1;
    h[2 * t] = base[2 * t] + hr0 - st0;          // D (mod 2^32)
    h[2 * t + 1] = base[2 * t + 1] + hr1 - st1;
    __syncthreads();
    // rank + stage (key-sorted within block)
    for (int e = e0 + t; e < e1; e += BIN_T) {
        int d = dst[e];
        int sc = src[e];
        int key = ((d >> SB_BITS) << 3) | ((sc >> 17) & 7);
        u32 r = atomicAdd(&cur[key], 1u);
        stage[r] = ((u32)(d & (SB - 1)) << 20) | (u32)sc;
        sbk[r] = (u8)(d >> SB_BITS);
    }
    __syncthreads();
    // flush: consecutive i -> consecutive global positions within runs
    for (int i = t; i < n; i += BIN_T) {
        u32 wv = stage[i];
        int key = ((int)sbk[i] << 3) | (int)((wv >> 17) & 7);
        bucketed[h[key] + (u32)i] = wv;
    }
}

// ---------------- aggregation (spec) ----------------

// agg1: f32 g-table (L2 gathers, request-bound). 490 blocks: bucket = bid>>1,
// dl-half = bid&1. Epilogue writes 2-bit classes packed into cls2.
__global__ __launch_bounds__(1024) void agg1_s(
        const u32* __restrict__ bucketed, const u32* __restrict__ base,
        const u32* __restrict__ T, const float* __restrict__ gt,
        u32* __restrict__ cls2, int N, const u32* __restrict__ flag) {
    if (*flag != 1u) return;
    __shared__ float acc[SB / 2];        // 8 KB
    int bid = blockIdx.x, t = threadIdx.x;
    int b = bid >> 1;
    u32 half = (u32)(bid & 1);
    acc[t] = 0.0f; acc[t + 1024] = 0.0f;
    __syncthreads();
    for (int sl = 0; sl < 8; ++sl) {
        int k = b * 8 + sl;
        u32 p0 = base[k], cnt = T[k];
        for (u32 q = 16u * (u32)t; q < cnt; q += 16384u) {
            const u32x4* p = (const u32x4*)(bucketed + p0 + q);
            u32 wv[16];
            #pragma unroll
            for (int j4 = 0; j4 < 4; ++j4) {
                u32x4 wq = __builtin_nontemporal_load(p + j4);
                wv[4 * j4] = wq[0]; wv[4 * j4 + 1] = wq[1];
                wv[4 * j4 + 2] = wq[2]; wv[4 * j4 + 3] = wq[3];
            }
            #pragma unroll
            for (int j = 0; j < 16; ++j) {
                u32 dl = wv[j] >> 20;
                bool act = (q + j < cnt) && ((dl >> 11) == half);
                if (act) {
                    u32 s = min(wv[j] & 0xFFFFFu, (u32)(N - 1));
                    float gv = gt[s];
                    atomicAdd(&acc[dl & 2047], gv);
                }
            }
        }
    }
    __syncthreads();
    // epilogue: pack classes 2-bit, 16 nodes/word, 128 words for this half
    int n0 = (b << SB_BITS) + (int)half * 2048;
    if (t < 128) {
        u32 word = 0;
        #pragma unroll
        for (int i = 0; i < 16; ++i) {
            float u = acc[t * 16 + i];
            u32 c = (u > 0.0f) ? 1u : ((u < 0.0f) ? 2u : 0u);
            word |= c << (2 * i);
        }
        cls2[(n0 >> 4) + t] = word;
    }
}

// agg2: 2-bit class table sliced 32 KB in LDS (zero L2 gather requests).
// Epilogue computes sigmoid output directly.
__global__ __launch_bounds__(1024) void agg2_s(
        const u32* __restrict__ bucketed, const u32* __restrict__ base,
        const u32* __restrict__ T, const u32* __restrict__ cls2,
        float* __restrict__ out, const float* __restrict__ W,
        const float* __restrict__ fw, int N, const u32* __restrict__ flag) {
    if (*flag != 1u) return;
    __shared__ u32 acc[SB];              // 16 KB (P<<16 | Q per node)
    __shared__ u32 tbl[8192];            // 32 KB (128K nodes x 2 bit)
    int b = blockIdx.x, t = threadIdx.x;
    #pragma unroll
    for (int j = 0; j < 4; ++j) acc[t + 1024 * j] = 0u;
    for (int sl = 0; sl < 8; ++sl) {
        __syncthreads();                 // prev slice reads done / acc init
        #pragma unroll
        for (int j = 0; j < 8; ++j)
            tbl[t + 1024 * j] = cls2[sl * 8192 + t + 1024 * j];
        __syncthreads();
        int k = b * 8 + sl;
        u32 p0 = base[k], cnt = T[k];
        for (u32 q = 8u * (u32)t; q < cnt; q += 8192u) {
            const u32x4* p = (const u32x4*)(bucketed + p0 + q);
            u32x4 wa = __builtin_nontemporal_load(p);
            u32x4 wb = __builtin_nontemporal_load(p + 1);
            u32 wv[8] = {wa[0], wa[1], wa[2], wa[3], wb[0], wb[1], wb[2], wb[3]};
            u32 av[8];
            #pragma unroll
            for (int j = 0; j < 8; ++j) {
                u32 local = wv[j] & 0x1FFFFu;           // 17-bit in-slice id
                u32 c = (tbl[local >> 4] >> (2 * (local & 15u))) & 3u;
                av[j] = (c == 1u) ? 65536u : ((c == 2u) ? 1u : 0u);
            }
            #pragma unroll
            for (int j = 0; j < 8; ++j)
                if (q + j < cnt && av[j])
                    atomicAdd(&acc[wv[j] >> 20], av[j]);
        }
    }
    __syncthreads();
    float w00 = W[4], w10 = W[6], f0 = fw[0], f1 = fw[1];
    int n0 = b << SB_BITS;
    for (int i = t; i < SB && n0 + i < N; i += 1024) {
        u32 cc = acc[i];
        float P = (float)(cc >> 16), Q = (float)(cc & 0xFFFFu);
        float u2 = w00 * P + w10 * Q;
        float z = f0 * fmaxf(u2, 0.0f) + f1 * fmaxf(-u2, 0.0f);
        out[n0 + i] = 1.0f / (1.0f + expf(-z));
    }
}

// general: float2 table -> float2 B (2 f32 LDS atomics/edge)
__global__ __launch_bounds__(1024) void agg_g(
        const u32* __restrict__ bucketed, const u32* __restrict__ base,
        const u32* __restrict__ T, const float2* __restrict__ A,
        float2* __restrict__ B, int N, const u32* __restrict__ flag) {
    if (*flag != 0u) return;
    __shared__ float acc[SB * 2];        // 32 KB
    int b = blockIdx.x, t = threadIdx.x;
    for (int i = t; i < SB * 2; i += 1024) acc[i] = 0.0f;
    __syncthreads();
    for (int sl = 0; sl < 8; ++sl) {
        int k = b * 8 + sl;
        u32 p0 = base[k], cnt = T[k];
        for (u32 q = 8u * (u32)t; q < cnt; q += 8192u) {
            const u32x4* p = (const u32x4*)(bucketed + p0 + q);
            u32x4 wa = __builtin_nontemporal_load(p);
            u32x4 wb = __builtin_nontemporal_load(p + 1);
            u32 wv[8] = {wa[0], wa[1], wa[2], wa[3], wb[0], wb[1], wb[2], wb[3]};
            float2 vv[8];
            #pragma unroll
            for (int j = 0; j < 8; ++j) {
                u32 s = min(wv[j] & 0xFFFFFu, (u32)(N - 1));
                vv[j] = A[s];
            }
            #pragma unroll
            for (int j = 0; j < 8; ++j) {
                if (q + j < cnt) {
                    int dl = (int)(wv[j] >> 20);
                    atomicAdd(&acc[2 * dl], vv[j].x);
                    atomicAdd(&acc[2 * dl + 1], vv[j].y);
                }
            }
        }
    }
    __syncthreads();
    int n0 = b << SB_BITS;
    for (int i = t; i < SB && n0 + i < N; i += 1024)
        B[n0 + i] = make_float2(acc[2 * i], acc[2 * i + 1]);
}

// ---------------- fallback: direct global-atomic scatter ----------------

__global__ void scatter_kernel(const int* __restrict__ src,
                               const int* __restrict__ dst,
                               const float2* __restrict__ A,
                               float* __restrict__ B, int E) {
    int tid = blockIdx.x * blockDim.x + threadIdx.x;
    int stride = gridDim.x * blockDim.x;
    for (int e = tid; e < E; e += stride) {
        int s = src[e];
        int d = dst[e];
        float2 v = A[s];
        atomicAdd(&B[2 * d], v.x);
        atomicAdd(&B[2 * d + 1], v.y);
    }
}

extern "C" void kernel_launch(void* const* d_in, const int* in_sizes, int n_in,
                              void* d_out, int out_size, void* d_ws, size_t ws_size,
                              hipStream_t stream) {
    const float* x = (const float*)d_in[0];          // [N,2]
    const int* edge_index = (const int*)d_in[1];     // [2,E]
    const float* W = (const float*)d_in[2];          // [2,2,2]
    const float* fw = (const float*)d_in[3];         // [2]
    float* out = (float*)d_out;                      // [N]

    const int N = in_sizes[0] / 2;
    const int E = in_sizes[1] / 2;
    const int* src = edge_index;       // row 0 = message source j
    const int* dst = edge_index + E;   // row 1 = aggregation target i

    const int NB = (N + SB - 1) >> SB_BITS;          // 245
    const int gridC = (E + CHUNK - 1) / CHUNK;       // 3907

    // workspace layout:
    //  U1 [0, 8MB): spec: g f32[N] | general: A0 float2[N]
    //  U2 [8MB, +max(H 16MB, B 8MB)): H u16[gridC*NBW] (dead before agg)
    //        spec: cls2 u32[65536] @+0 | general: B float2[N]
    //  bucketed u32[E + 8192] | T u32[NBW] | base u32[NBW+1] | flag u32
    char* ws = (char*)d_ws;
    size_t aBytes = (size_t)N * 2 * sizeof(float);           // 8 MB
    size_t hBytes = (size_t)gridC * NBW * sizeof(u16);       // ~16 MB
    size_t bBytes = (size_t)N * 2 * sizeof(float);           // 8 MB
    size_t uBytes = (hBytes > bBytes ? hBytes : bBytes);

    float* g    = (float*)ws;
    float2* A0  = (float2*)ws;
    u16*  H     = (u16*)(ws + aBytes);
    u32*  cls2  = (u32*)(ws + aBytes);                       // 256 KB, aliases H
    float* Bg   = (float*)(ws + aBytes);
    u32* bucketed = (u32*)(ws + aBytes + uBytes);            // [E + 8192]
    u32* T    = bucketed + (size_t)E + 8192;                 // [NBW]
    u32* base = T + NBW;                                     // [NBW+1]
    u32* flag = base + NBW + 1;
    size_t need = (char*)(flag + 1) - ws;

    const int BLK = 256;
    const int gridN = (N + BLK - 1) / BLK;

    flag_k<<<1, 1, 0, stream>>>(W, flag);

    if (ws_size >= need && 8 * NB <= NBW && N <= (1 << 20) && E <= (1 << 25)) {
        // tables (flag-gated; disjoint use of U1)
        g_k<<<gridN, BLK, 0, stream>>>((const float2*)x, W, g, N, flag);
        norm_input_kernel<<<gridN, BLK, 0, stream>>>((const float2*)x, A0, N,
                                                     flag, 0);
        // partition (flag-independent)
        hist_k<<<gridC, BIN_T, 0, stream>>>(src, dst, E, gridC, H);
        colscan_k<<<NBW / SCAN_BK, 256, 0, stream>>>(H, gridC, T);
        base_k<<<1, 512, 0, stream>>>(T, base);
        bin_k<<<gridC, BIN_T, 0, stream>>>(src, dst, E, gridC, H, base,
                                           bucketed);
        // iter 1: spec f32 gathers -> 2-bit classes; general float2 path
        agg1_s<<<2 * NB, 1024, 0, stream>>>(bucketed, base, T, g, cls2, N, flag);
        agg_g<<<NB, 1024, 0, stream>>>(bucketed, base, T, (const float2*)A0,
                                       (float2*)Bg, N, flag);
        wrelu_norm_kernel<<<gridN, BLK, 0, stream>>>((const float2*)Bg, A0, W,
                                                     N, flag, 0);
        // iter 2: spec LDS-staged 2-bit gathers, fused sigmoid epilogue
        agg2_s<<<NB, 1024, 0, stream>>>(bucketed, base, T, cls2, out, W, fw,
                                        N, flag);
        agg_g<<<NB, 1024, 0, stream>>>(bucketed, base, T, (const float2*)A0,
                                       (float2*)Bg, N, flag);
        wrelu_sig_kernel<<<gridN, BLK, 0, stream>>>((const float2*)Bg, out,
                                                    W + 4, fw, N, flag, 0);
    } else {
        // fallback: direct atomic scatter (generic, flag-independent)
        float* B = (float*)(ws + aBytes);
        const size_t featBytes = (size_t)N * 2 * sizeof(float);
        const int gridE = 8192;
        norm_input_kernel<<<gridN, BLK, 0, stream>>>((const float2*)x, A0, N,
                                                     flag, -1);
        hipMemsetAsync(B, 0, featBytes, stream);
        scatter_kernel<<<gridE, BLK, 0, stream>>>(src, dst, (const float2*)A0,
                                                  B, E);
        wrelu_norm_kernel<<<gridN, BLK, 0, stream>>>((const float2*)B, A0, W,
                                                     N, flag, -1);
        hipMemsetAsync(B, 0, featBytes, stream);
        scatter_kernel<<<gridE, BLK, 0, stream>>>(src, dst, (const float2*)A0,
                                                  B, E);
        wrelu_sig_kernel<<<gridN, BLK, 0, stream>>>((const float2*)B, out,
                                                    W + 4, fw, N, flag, -1);
    }
}

// Round 9
// 495.436 us; speedup vs baseline: 1.2326x; 1.0339x over previous
//
#include <hip/hip_runtime.h>
#include <math.h>

// 2 iterations of {row-L2-normalize -> scatter-add over 32M edges -> 2x2 matmul
// + ReLU}, then sigmoid(x @ final_weight). N = 1M nodes, E = 32M edges.
//
// Spec path (device-verified: W col1 == -col0 both iters): iter1 aggregates
// g[src] (f32 L2 gathers; pinned at the ~72 line-req/cyc device ceiling ->
// ~185us floor); iter2's table is ternary 2-bit (256 KB), 32 KB slices staged
// in LDS (zero L2 gather requests). Both aggs slice-split 2 blocks/bucket
// (490 blocks, 32 waves/CU — R6 lesson: occupancy is the lever), partials
// merged by tiny kernels. Partition key = dst_bucket(4096)*8 + (src>>17).

#define EPS 1e-15f
#define SB_BITS 12
#define SB 4096              // dst nodes per bucket (NB = 245)
#define NBW 2048             // padded key width (real = 245*8 = 1960)
#define CHUNK 8192           // edges per partition block
#define BIN_T 1024
#define SCAN_BK 8

typedef unsigned int u32;
typedef unsigned short u16;
typedef unsigned char u8;
typedef unsigned int u32x4 __attribute__((ext_vector_type(4)));

// XCD-contiguous chunk id: consecutive chunks land on the same XCD
__device__ inline int chunk_id(int bid, int gridC) {
    int q = gridC >> 3, r = gridC & 7;
    int x = bid & 7, i = bid >> 3;
    int base = (x < r) ? x * (q + 1) : r * (q + 1) + (x - r) * q;
    return base + i;
}

// ---------------- flag: does W have the col1 == -col0 property? ----------------

__global__ void flag_k(const float* __restrict__ W, u32* __restrict__ flag) {
    bool ok = (W[1] == -W[0]) && (W[3] == -W[2]) &&
              (W[5] == -W[4]) && (W[7] == -W[6]);
    *flag = ok ? 1u : 0u;
}

// ---------------- node-wise kernels ----------------

// spec: g[n] = (w00*x.x + w10*x.y) / (|x| + eps)
__global__ void g_k(const float2* __restrict__ x, const float* __restrict__ W,
                    float* __restrict__ g, int N, const u32* __restrict__ flag) {
    if (*flag != 1u) return;
    int n = blockIdx.x * blockDim.x + threadIdx.x;
    if (n >= N) return;
    float2 v = x[n];
    float nm = sqrtf(v.x * v.x + v.y * v.y);
    float inv = 1.0f / (nm + EPS);
    g[n] = (W[0] * v.x + W[2] * v.y) * inv;
}

// general/fallback: normalize x into A (want: -1 = always, else require *flag==want)
__global__ void norm_input_kernel(const float2* __restrict__ x,
                                  float2* __restrict__ A, int N,
                                  const u32* __restrict__ flag, int want) {
    if (want >= 0 && *flag != (u32)want) return;
    int n = blockIdx.x * blockDim.x + threadIdx.x;
    if (n >= N) return;
    float2 v = x[n];
    float nm = sqrtf(v.x * v.x + v.y * v.y);
    float inv = 1.0f / (nm + EPS);
    A[n] = make_float2(v.x * inv, v.y * inv);
}

// general/fallback: A = normalize(relu(B @ W))
__global__ void wrelu_norm_kernel(const float2* __restrict__ B,
                                  float2* __restrict__ A,
                                  const float* __restrict__ W, int N,
                                  const u32* __restrict__ flag, int want) {
    if (want >= 0 && *flag != (u32)want) return;
    int n = blockIdx.x * blockDim.x + threadIdx.x;
    if (n >= N) return;
    float w00 = W[0], w01 = W[1], w10 = W[2], w11 = W[3];
    float2 b = B[n];
    float y0 = fmaxf(b.x * w00 + b.y * w10, 0.0f);
    float y1 = fmaxf(b.x * w01 + b.y * w11, 0.0f);
    float nm = sqrtf(y0 * y0 + y1 * y1);
    float inv = 1.0f / (nm + EPS);
    A[n] = make_float2(y0 * inv, y1 * inv);
}

// general/fallback: out = sigmoid(relu(B @ W) . fw)
__global__ void wrelu_sig_kernel(const float2* __restrict__ B,
                                 float* __restrict__ out,
                                 const float* __restrict__ W,
                                 const float* __restrict__ fw, int N,
                                 const u32* __restrict__ flag, int want) {
    if (want >= 0 && *flag != (u32)want) return;
    int n = blockIdx.x * blockDim.x + threadIdx.x;
    if (n >= N) return;
    float w00 = W[0], w01 = W[1], w10 = W[2], w11 = W[3];
    float f0 = fw[0], f1 = fw[1];
    float2 b = B[n];
    float y0 = fmaxf(b.x * w00 + b.y * w10, 0.0f);
    float y1 = fmaxf(b.x * w01 + b.y * w11, 0.0f);
    float z = y0 * f0 + y1 * f1;
    out[n] = 1.0f / (1.0f + expf(-z));
}

// spec: merge u1 partials -> 2-bit class table (16 nodes/word)
__global__ void merge1_k(const float* __restrict__ u1part,
                         u32* __restrict__ cls2, int N,
                         const u32* __restrict__ flag) {
    if (*flag != 1u) return;
    int w = blockIdx.x * blockDim.x + threadIdx.x;
    if (w >= 65536) return;
    const float* p0 = u1part;
    const float* p1 = u1part + N;
    u32 word = 0;
    #pragma unroll
    for (int i = 0; i < 16; ++i) {
        int n = w * 16 + i;
        u32 c = 0;
        if (n < N) {
            float u = p0[n] + p1[n];
            c = (u > 0.0f) ? 1u : ((u < 0.0f) ? 2u : 0u);
        }
        word |= c << (2 * i);
    }
    cls2[w] = word;
}

// spec: merge packed count partials + sigmoid epilogue
__global__ void final2_k(const u32* __restrict__ cntpart,
                         float* __restrict__ out, const float* __restrict__ W,
                         const float* __restrict__ fw, int N,
                         const u32* __restrict__ flag) {
    if (*flag != 1u) return;
    int n = blockIdx.x * blockDim.x + threadIdx.x;
    if (n >= N) return;
    u32 cc = cntpart[n] + cntpart[n + N];   // fields don't cross-carry
    float P = (float)(cc >> 16), Q = (float)(cc & 0xFFFFu);
    float u2 = W[4] * P + W[6] * Q;
    float z = fw[0] * fmaxf(u2, 0.0f) + fw[1] * fmaxf(-u2, 0.0f);
    out[n] = 1.0f / (1.0f + expf(-z));
}

// ---------------- partition pipeline (flag-independent) ----------------

// P0: per-(chunk,key) histogram, chunk-major H[cid][key]
__global__ __launch_bounds__(BIN_T) void hist_k(const int* __restrict__ src,
                                                const int* __restrict__ dst,
                                                int E, int gridC,
                                                u16* __restrict__ H) {
    __shared__ u32 h[NBW];
    int t = threadIdx.x;
    h[t] = 0; h[t + 1024] = 0;
    __syncthreads();
    int cid = chunk_id(blockIdx.x, gridC);
    int e0 = cid * CHUNK, e1 = min(E, e0 + CHUNK);
    for (int e = e0 + t; e < e1; e += BIN_T) {
        int key = ((dst[e] >> SB_BITS) << 3) | ((src[e] >> 17) & 7);
        atomicAdd(&h[key], 1u);
    }
    __syncthreads();
    u16* row = H + (size_t)cid * NBW;
    row[t] = (u16)h[t];
    row[t + 1024] = (u16)h[t + 1024];
}

// P1: in-place exclusive scan of H along chunks, per key; totals -> T
__global__ void colscan_k(u16* __restrict__ H, int gridC, u32* __restrict__ T) {
    __shared__ u32 tile[SCAN_BK][257];
    __shared__ u32 carry[SCAN_BK];
    int t = threadIdx.x;                // 256
    int b0 = blockIdx.x * SCAN_BK;
    if (t < SCAN_BK) carry[t] = 0;
    __syncthreads();
    int w = t >> 6, lane = t & 63;
    int rounds = (gridC + 255) / 256;
    for (int i = 0; i < rounds; ++i) {
        int blk = i * 256 + t;
        u32 vals[SCAN_BK];
        #pragma unroll
        for (int j = 0; j < SCAN_BK; ++j) vals[j] = 0;
        if (blk < gridC) {
            const u16* p = H + (size_t)blk * NBW + b0;
            uint4 v = *(const uint4*)p;     // 8 x u16
            vals[0] = v.x & 0xFFFFu; vals[1] = v.x >> 16;
            vals[2] = v.y & 0xFFFFu; vals[3] = v.y >> 16;
            vals[4] = v.z & 0xFFFFu; vals[5] = v.z >> 16;
            vals[6] = v.w & 0xFFFFu; vals[7] = v.w >> 16;
        }
        #pragma unroll
        for (int j = 0; j < SCAN_BK; ++j) tile[j][t] = vals[j];
        __syncthreads();
        for (int c = w * 2; c < w * 2 + 2; ++c) {
            u32 cb = carry[c];
            u32 run = 0;
            for (int seg = 0; seg < 4; ++seg) {
                u32 x = tile[c][seg * 64 + lane];
                u32 inc = x;
                for (int off = 1; off < 64; off <<= 1) {
                    u32 y = __shfl_up(inc, off);
                    if (lane >= off) inc += y;
                }
                tile[c][seg * 64 + lane] = inc - x + run + cb;
                run += __shfl(inc, 63);
            }
            if (lane == 0) carry[c] = cb + run;
        }
        __syncthreads();
        if (blk < gridC) {
            #pragma unroll
            for (int j = 0; j < SCAN_BK; ++j) vals[j] = tile[j][t];
            u16* p = H + (size_t)blk * NBW + b0;
            uint4 v;
            v.x = vals[0] | (vals[1] << 16);
            v.y = vals[2] | (vals[3] << 16);
            v.z = vals[4] | (vals[5] << 16);
            v.w = vals[6] | (vals[7] << 16);
            *(uint4*)p = v;
        }
        __syncthreads();
    }
    if (t < SCAN_BK) T[b0 + t] = carry[t];
}

// P2: key bases, rounded to 4 words (16B) for vectorized agg loads
__global__ __launch_bounds__(512) void base_k(const u32* __restrict__ T,
                                              u32* __restrict__ base) {
    __shared__ u32 wp[8];
    int t = threadIdx.x;                // 512, VPT = 4
    u32 loc[4];
    u32 s = 0;
    #pragma unroll
    for (int j = 0; j < 4; ++j) {
        loc[j] = (T[t * 4 + j] + 3u) & ~3u;
        s += loc[j];
    }
    int lane = t & 63, w = t >> 6;
    u32 inc = s;
    for (int off = 1; off < 64; off <<= 1) {
        u32 y = __shfl_up(inc, off);
        if (lane >= off) inc += y;
    }
    if (lane == 63) wp[w] = inc;
    __syncthreads();
    u32 add = 0;
    for (int j = 0; j < w; ++j) add += wp[j];
    u32 run = inc - s + add;
    #pragma unroll
    for (int j = 0; j < 4; ++j) {
        base[t * 4 + j] = run;
        run += loc[j];
    }
    if (t == 511) base[NBW] = run;
}

// P3: block-local key sort in LDS, then coalesced run flush (~57 KB LDS)
__global__ __launch_bounds__(BIN_T) void bin_k(const int* __restrict__ src,
                                               const int* __restrict__ dst,
                                               int E, int gridC,
                                               const u16* __restrict__ H,
                                               const u32* __restrict__ base,
                                               u32* __restrict__ bucketed) {
    __shared__ u32 h[NBW];               // counts, then D = base + Hrow - start
    __shared__ u32 cur[NBW];
    __shared__ u32 stage[CHUNK];         // 32 KB
    __shared__ u8 sbk[CHUNK];            // 8 KB (dst bucket, < 256)
    __shared__ u32 wp[16];
    int t = threadIdx.x;                 // 1024
    int cid = chunk_id(blockIdx.x, gridC);
    int e0 = cid * CHUNK, e1 = min(E, e0 + CHUNK), n = e1 - e0;
    h[t] = 0; h[t + 1024] = 0;
    __syncthreads();
    for (int e = e0 + t; e < e1; e += BIN_T) {
        int key = ((dst[e] >> SB_BITS) << 3) | ((src[e] >> 17) & 7);
        atomicAdd(&h[key], 1u);
    }
    __syncthreads();
    // exclusive scan h -> start (2 keys per thread)
    u32 loc0 = h[2 * t], loc1 = h[2 * t + 1];
    u32 s = loc0 + loc1;
    int lane = t & 63, w = t >> 6;
    u32 inc = s;
    for (int off = 1; off < 64; off <<= 1) {
        u32 y = __shfl_up(inc, off);
        if (lane >= off) inc += y;
    }
    if (lane == 63) wp[w] = inc;
    __syncthreads();
    u32 add = 0;
    for (int j = 0; j < w; ++j) add += wp[j];
    u32 run = inc - s + add;
    const u16* Hrow = H + (size_t)cid * NBW;
    u32 st0 = run, st1 = run + loc0;
    u32 hr0 = (u32)Hrow[2 * t], hr1 = (u32)Hrow[2 * t + 1];
    __syncthreads();                     // counts consumed before h overwrite
    cur[2 * t] = st0;
    cur[2 * t + 1] = st1;
    h[2 * t] = base[2 * t] + hr0 - st0;          // D (mod 2^32)
    h[2 * t + 1] = base[2 * t + 1] + hr1 - st1;
    __syncthreads();
    // rank + stage (key-sorted within block)
    for (int e = e0 + t; e < e1; e += BIN_T) {
        int d = dst[e];
        int sc = src[e];
        int key = ((d >> SB_BITS) << 3) | ((sc >> 17) & 7);
        u32 r = atomicAdd(&cur[key], 1u);
        stage[r] = ((u32)(d & (SB - 1)) << 20) | (u32)sc;
        sbk[r] = (u8)(d >> SB_BITS);
    }
    __syncthreads();
    // flush: consecutive i -> consecutive global positions within runs
    for (int i = t; i < n; i += BIN_T) {
        u32 wv = stage[i];
        int key = ((int)sbk[i] << 3) | (int)((wv >> 17) & 7);
        bucketed[h[key] + (u32)i] = wv;
    }
}

// ---------------- aggregation (spec) ----------------

// agg1: f32 g-table, L2 gathers (request-rate floor). Slice-split:
// block (b,h) owns slices {h, h+2, h+4, h+6}; partials to u1part[h][N].
__global__ __launch_bounds__(1024) void agg1_s(
        const u32* __restrict__ bucketed, const u32* __restrict__ base,
        const u32* __restrict__ T, const float* __restrict__ gt,
        float* __restrict__ u1part, int N, const u32* __restrict__ flag) {
    if (*flag != 1u) return;
    __shared__ float acc[SB];            // 16 KB
    int bid = blockIdx.x, t = threadIdx.x;
    int b = bid >> 1, h = bid & 1;
    acc[t] = 0.0f; acc[t + 1024] = 0.0f;
    acc[t + 2048] = 0.0f; acc[t + 3072] = 0.0f;
    __syncthreads();
    for (int si = 0; si < 4; ++si) {
        int k = b * 8 + h + 2 * si;      // interleaved slices
        u32 p0 = base[k], cnt = T[k];
        for (u32 q = 8u * (u32)t; q < cnt; q += 8192u) {
            const u32x4* p = (const u32x4*)(bucketed + p0 + q);
            u32x4 wa = __builtin_nontemporal_load(p);
            u32x4 wb = __builtin_nontemporal_load(p + 1);
            u32 wv[8] = {wa[0], wa[1], wa[2], wa[3], wb[0], wb[1], wb[2], wb[3]};
            float gv[8];
            #pragma unroll
            for (int j = 0; j < 8; ++j) {
                u32 s = min(wv[j] & 0xFFFFFu, (u32)(N - 1));
                gv[j] = gt[s];
            }
            #pragma unroll
            for (int j = 0; j < 8; ++j)
                if (q + j < cnt)
                    atomicAdd(&acc[wv[j] >> 20], gv[j]);
        }
    }
    __syncthreads();
    int n0 = b << SB_BITS;
    float* dstp = u1part + (size_t)h * N + n0;
    for (int i = t; i < SB && n0 + i < N; i += 1024) dstp[i] = acc[i];
}

// agg2: 2-bit class table, 32 KB LDS slices (zero L2 gather requests).
// Slice-split like agg1; packed count partials to cntpart[h][N].
__global__ __launch_bounds__(1024) void agg2_s(
        const u32* __restrict__ bucketed, const u32* __restrict__ base,
        const u32* __restrict__ T, const u32* __restrict__ cls2,
        u32* __restrict__ cntpart, int N, const u32* __restrict__ flag) {
    if (*flag != 1u) return;
    __shared__ u32 acc[SB];              // 16 KB
    __shared__ u32 tbl[8192];            // 32 KB
    int bid = blockIdx.x, t = threadIdx.x;
    int b = bid >> 1, h = bid & 1;
    acc[t] = 0u; acc[t + 1024] = 0u;
    acc[t + 2048] = 0u; acc[t + 3072] = 0u;
    for (int si = 0; si < 4; ++si) {
        int sl = h + 2 * si;
        __syncthreads();                 // prev slice reads done / acc init
        #pragma unroll
        for (int j = 0; j < 8; ++j)
            tbl[t + 1024 * j] = cls2[sl * 8192 + t + 1024 * j];
        __syncthreads();
        int k = b * 8 + sl;
        u32 p0 = base[k], cnt = T[k];
        for (u32 q = 8u * (u32)t; q < cnt; q += 8192u) {
            const u32x4* p = (const u32x4*)(bucketed + p0 + q);
            u32x4 wa = __builtin_nontemporal_load(p);
            u32x4 wb = __builtin_nontemporal_load(p + 1);
            u32 wv[8] = {wa[0], wa[1], wa[2], wa[3], wb[0], wb[1], wb[2], wb[3]};
            u32 av[8];
            #pragma unroll
            for (int j = 0; j < 8; ++j) {
                u32 local = wv[j] & 0x1FFFFu;           // 17-bit in-slice id
                u32 c = (tbl[local >> 4] >> (2 * (local & 15u))) & 3u;
                av[j] = (c == 1u) ? 65536u : ((c == 2u) ? 1u : 0u);
            }
            #pragma unroll
            for (int j = 0; j < 8; ++j)
                if (q + j < cnt && av[j])
                    atomicAdd(&acc[wv[j] >> 20], av[j]);
        }
    }
    __syncthreads();
    int n0 = b << SB_BITS;
    u32* dstp = cntpart + (size_t)h * N + n0;
    for (int i = t; i < SB && n0 + i < N; i += 1024) dstp[i] = acc[i];
}

// general: float2 table -> float2 B (2 f32 LDS atomics/edge)
__global__ __launch_bounds__(1024) void agg_g(
        const u32* __restrict__ bucketed, const u32* __restrict__ base,
        const u32* __restrict__ T, const float2* __restrict__ A,
        float2* __restrict__ B, int N, const u32* __restrict__ flag) {
    if (*flag != 0u) return;
    __shared__ float acc[SB * 2];        // 32 KB
    int b = blockIdx.x, t = threadIdx.x;
    for (int i = t; i < SB * 2; i += 1024) acc[i] = 0.0f;
    __syncthreads();
    for (int sl = 0; sl < 8; ++sl) {
        int k = b * 8 + sl;
        u32 p0 = base[k], cnt = T[k];
        for (u32 q = 8u * (u32)t; q < cnt; q += 8192u) {
            const u32x4* p = (const u32x4*)(bucketed + p0 + q);
            u32x4 wa = __builtin_nontemporal_load(p);
            u32x4 wb = __builtin_nontemporal_load(p + 1);
            u32 wv[8] = {wa[0], wa[1], wa[2], wa[3], wb[0], wb[1], wb[2], wb[3]};
            float2 vv[8];
            #pragma unroll
            for (int j = 0; j < 8; ++j) {
                u32 s = min(wv[j] & 0xFFFFFu, (u32)(N - 1));
                vv[j] = A[s];
            }
            #pragma unroll
            for (int j = 0; j < 8; ++j) {
                if (q + j < cnt) {
                    int dl = (int)(wv[j] >> 20);
                    atomicAdd(&acc[2 * dl], vv[j].x);
                    atomicAdd(&acc[2 * dl + 1], vv[j].y);
                }
            }
        }
    }
    __syncthreads();
    int n0 = b << SB_BITS;
    for (int i = t; i < SB && n0 + i < N; i += 1024)
        B[n0 + i] = make_float2(acc[2 * i], acc[2 * i + 1]);
}

// ---------------- fallback: direct global-atomic scatter ----------------

__global__ void scatter_kernel(const int* __restrict__ src,
                               const int* __restrict__ dst,
                               const float2* __restrict__ A,
                               float* __restrict__ B, int E) {
    int tid = blockIdx.x * blockDim.x + threadIdx.x;
    int stride = gridDim.x * blockDim.x;
    for (int e = tid; e < E; e += stride) {
        int s = src[e];
        int d = dst[e];
        float2 v = A[s];
        atomicAdd(&B[2 * d], v.x);
        atomicAdd(&B[2 * d + 1], v.y);
    }
}

extern "C" void kernel_launch(void* const* d_in, const int* in_sizes, int n_in,
                              void* d_out, int out_size, void* d_ws, size_t ws_size,
                              hipStream_t stream) {
    const float* x = (const float*)d_in[0];          // [N,2]
    const int* edge_index = (const int*)d_in[1];     // [2,E]
    const float* W = (const float*)d_in[2];          // [2,2,2]
    const float* fw = (const float*)d_in[3];         // [2]
    float* out = (float*)d_out;                      // [N]

    const int N = in_sizes[0] / 2;
    const int E = in_sizes[1] / 2;
    const int* src = edge_index;       // row 0 = message source j
    const int* dst = edge_index + E;   // row 1 = aggregation target i

    const int NB = (N + SB - 1) >> SB_BITS;          // 245
    const int gridC = (E + CHUNK - 1) / CHUNK;       // 3907

    // workspace layout:
    //  U1 [0, 8MB): spec: g f32[N] | general: A0 float2[N]
    //  U2 [8MB, +uBytes): H u16[gridC*NBW] (dead before agg writes)
    //     spec: u1part f32[2][N] @+0 (later cntpart u32[2][N] @+0),
    //           cls2 u32[65536] @+2N*4 | general: Bg float2[N] @+0
    //  bucketed u32[E + 8192] | T u32[NBW] | base u32[NBW+1] | flag u32
    char* ws = (char*)d_ws;
    size_t aBytes = (size_t)N * 2 * sizeof(float);           // 8 MB
    size_t hBytes = (size_t)gridC * NBW * sizeof(u16);       // ~16 MB
    size_t pBytes = (size_t)N * 2 * sizeof(float) + 262144;  // partials + cls2
    size_t uBytes = hBytes > pBytes ? hBytes : pBytes;

    float* g    = (float*)ws;
    float2* A0  = (float2*)ws;
    char* U2    = ws + aBytes;
    u16*  H       = (u16*)U2;
    float* u1part = (float*)U2;                              // [2][N]
    u32*  cntpart = (u32*)U2;                                // [2][N]
    u32*  cls2    = (u32*)(U2 + (size_t)N * 2 * sizeof(float)); // 256 KB
    float* Bg     = (float*)U2;
    u32* bucketed = (u32*)(U2 + uBytes);                     // [E + 8192]
    u32* T    = bucketed + (size_t)E + 8192;                 // [NBW]
    u32* base = T + NBW;                                     // [NBW+1]
    u32* flag = base + NBW + 1;
    size_t need = (char*)(flag + 1) - ws;

    const int BLK = 256;
    const int gridN = (N + BLK - 1) / BLK;

    flag_k<<<1, 1, 0, stream>>>(W, flag);

    if (ws_size >= need && 8 * NB <= NBW && N <= (1 << 20) && E <= (1 << 25)) {
        // tables (flag-gated; disjoint use of U1)
        g_k<<<gridN, BLK, 0, stream>>>((const float2*)x, W, g, N, flag);
        norm_input_kernel<<<gridN, BLK, 0, stream>>>((const float2*)x, A0, N,
                                                     flag, 0);
        // partition (flag-independent)
        hist_k<<<gridC, BIN_T, 0, stream>>>(src, dst, E, gridC, H);
        colscan_k<<<NBW / SCAN_BK, 256, 0, stream>>>(H, gridC, T);
        base_k<<<1, 512, 0, stream>>>(T, base);
        bin_k<<<gridC, BIN_T, 0, stream>>>(src, dst, E, gridC, H, base,
                                           bucketed);
        // iter 1: spec f32 gathers -> u1 partials -> 2-bit classes
        agg1_s<<<2 * NB, 1024, 0, stream>>>(bucketed, base, T, g, u1part, N,
                                            flag);
        merge1_k<<<65536 / BLK, BLK, 0, stream>>>(u1part, cls2, N, flag);
        agg_g<<<NB, 1024, 0, stream>>>(bucketed, base, T, (const float2*)A0,
                                       (float2*)Bg, N, flag);
        wrelu_norm_kernel<<<gridN, BLK, 0, stream>>>((const float2*)Bg, A0, W,
                                                     N, flag, 0);
        // iter 2: spec LDS-staged 2-bit gathers -> count partials -> sigmoid
        agg2_s<<<2 * NB, 1024, 0, stream>>>(bucketed, base, T, cls2, cntpart,
                                            N, flag);
        final2_k<<<gridN, BLK, 0, stream>>>(cntpart, out, W, fw, N, flag);
        agg_g<<<NB, 1024, 0, stream>>>(bucketed, base, T, (const float2*)A0,
                                       (float2*)Bg, N, flag);
        wrelu_sig_kernel<<<gridN, BLK, 0, stream>>>((const float2*)Bg, out,
                                                    W + 4, fw, N, flag, 0);
    } else {
        // fallback: direct atomic scatter (generic, flag-independent)
        float* B = (float*)(ws + aBytes);
        const size_t featBytes = (size_t)N * 2 * sizeof(float);
        const int gridE = 8192;
        norm_input_kernel<<<gridN, BLK, 0, stream>>>((const float2*)x, A0, N,
                                                     flag, -1);
        hipMemsetAsync(B, 0, featBytes, stream);
        scatter_kernel<<<gridE, BLK, 0, stream>>>(src, dst, (const float2*)A0,
                                                  B, E);
        wrelu_norm_kernel<<<gridN, BLK, 0, stream>>>((const float2*)B, A0, W,
                                                     N, flag, -1);
        hipMemsetAsync(B, 0, featBytes, stream);
        scatter_kernel<<<gridE, BLK, 0, stream>>>(src, dst, (const float2*)A0,
                                                  B, E);
        wrelu_sig_kernel<<<gridN, BLK, 0, stream>>>((const float2*)B, out,
                                                    W + 4, fw, N, flag, -1);
    }
}

// Round 10
// 469.231 us; speedup vs baseline: 1.3014x; 1.0558x over previous
//
#include <hip/hip_runtime.h>
#include <math.h>

// 2 iterations of {row-L2-normalize -> scatter-add over 32M edges -> 2x2 matmul
// + ReLU}, then sigmoid(x @ final_weight). N = 1M nodes, E = 32M edges.
//
// Spec path (device-verified: W col1 == -col0 both iters): iter1 aggregates
// g[src] (f32 L2 gathers; pinned at the ~72 line-req/cyc device ceiling ->
// ~190us floor, confirmed R9); iter2's table is ternary 2-bit (256 KB), 32 KB
// slices staged in LDS (zero L2 gather requests). Both aggs slice-split
// 2 blocks/bucket (490 blocks, 32 waves/CU). R10: bin_k derives per-chunk key
// counts from H prefix differences (count[cid][k] = H[cid+1][k]-H[cid][k])
// instead of re-counting -> single edge pass, no count-pass LDS atomics.

#define EPS 1e-15f
#define SB_BITS 12
#define SB 4096              // dst nodes per bucket (NB = 245)
#define NBW 2048             // padded key width (real = 245*8 = 1960)
#define CHUNK 8192           // edges per partition block
#define BIN_T 1024
#define SCAN_BK 8

typedef unsigned int u32;
typedef unsigned short u16;
typedef unsigned char u8;
typedef unsigned int u32x4 __attribute__((ext_vector_type(4)));

// XCD-contiguous chunk id: consecutive chunks land on the same XCD
__device__ inline int chunk_id(int bid, int gridC) {
    int q = gridC >> 3, r = gridC & 7;
    int x = bid & 7, i = bid >> 3;
    int base = (x < r) ? x * (q + 1) : r * (q + 1) + (x - r) * q;
    return base + i;
}

// ---------------- flag: does W have the col1 == -col0 property? ----------------

__global__ void flag_k(const float* __restrict__ W, u32* __restrict__ flag) {
    bool ok = (W[1] == -W[0]) && (W[3] == -W[2]) &&
              (W[5] == -W[4]) && (W[7] == -W[6]);
    *flag = ok ? 1u : 0u;
}

// ---------------- node-wise kernels ----------------

// spec: g[n] = (w00*x.x + w10*x.y) / (|x| + eps)
__global__ void g_k(const float2* __restrict__ x, const float* __restrict__ W,
                    float* __restrict__ g, int N, const u32* __restrict__ flag) {
    if (*flag != 1u) return;
    int n = blockIdx.x * blockDim.x + threadIdx.x;
    if (n >= N) return;
    float2 v = x[n];
    float nm = sqrtf(v.x * v.x + v.y * v.y);
    float inv = 1.0f / (nm + EPS);
    g[n] = (W[0] * v.x + W[2] * v.y) * inv;
}

// general/fallback: normalize x into A (want: -1 = always, else require *flag==want)
__global__ void norm_input_kernel(const float2* __restrict__ x,
                                  float2* __restrict__ A, int N,
                                  const u32* __restrict__ flag, int want) {
    if (want >= 0 && *flag != (u32)want) return;
    int n = blockIdx.x * blockDim.x + threadIdx.x;
    if (n >= N) return;
    float2 v = x[n];
    float nm = sqrtf(v.x * v.x + v.y * v.y);
    float inv = 1.0f / (nm + EPS);
    A[n] = make_float2(v.x * inv, v.y * inv);
}

// general/fallback: A = normalize(relu(B @ W))
__global__ void wrelu_norm_kernel(const float2* __restrict__ B,
                                  float2* __restrict__ A,
                                  const float* __restrict__ W, int N,
                                  const u32* __restrict__ flag, int want) {
    if (want >= 0 && *flag != (u32)want) return;
    int n = blockIdx.x * blockDim.x + threadIdx.x;
    if (n >= N) return;
    float w00 = W[0], w01 = W[1], w10 = W[2], w11 = W[3];
    float2 b = B[n];
    float y0 = fmaxf(b.x * w00 + b.y * w10, 0.0f);
    float y1 = fmaxf(b.x * w01 + b.y * w11, 0.0f);
    float nm = sqrtf(y0 * y0 + y1 * y1);
    float inv = 1.0f / (nm + EPS);
    A[n] = make_float2(y0 * inv, y1 * inv);
}

// general/fallback: out = sigmoid(relu(B @ W) . fw)
__global__ void wrelu_sig_kernel(const float2* __restrict__ B,
                                 float* __restrict__ out,
                                 const float* __restrict__ W,
                                 const float* __restrict__ fw, int N,
                                 const u32* __restrict__ flag, int want) {
    if (want >= 0 && *flag != (u32)want) return;
    int n = blockIdx.x * blockDim.x + threadIdx.x;
    if (n >= N) return;
    float w00 = W[0], w01 = W[1], w10 = W[2], w11 = W[3];
    float f0 = fw[0], f1 = fw[1];
    float2 b = B[n];
    float y0 = fmaxf(b.x * w00 + b.y * w10, 0.0f);
    float y1 = fmaxf(b.x * w01 + b.y * w11, 0.0f);
    float z = y0 * f0 + y1 * f1;
    out[n] = 1.0f / (1.0f + expf(-z));
}

// spec: merge u1 partials -> 2-bit class table (16 nodes/word)
__global__ void merge1_k(const float* __restrict__ u1part,
                         u32* __restrict__ cls2, int N,
                         const u32* __restrict__ flag) {
    if (*flag != 1u) return;
    int w = blockIdx.x * blockDim.x + threadIdx.x;
    if (w >= 65536) return;
    const float* p0 = u1part;
    const float* p1 = u1part + N;
    u32 word = 0;
    #pragma unroll
    for (int i = 0; i < 16; ++i) {
        int n = w * 16 + i;
        u32 c = 0;
        if (n < N) {
            float u = p0[n] + p1[n];
            c = (u > 0.0f) ? 1u : ((u < 0.0f) ? 2u : 0u);
        }
        word |= c << (2 * i);
    }
    cls2[w] = word;
}

// spec: merge packed count partials + sigmoid epilogue
__global__ void final2_k(const u32* __restrict__ cntpart,
                         float* __restrict__ out, const float* __restrict__ W,
                         const float* __restrict__ fw, int N,
                         const u32* __restrict__ flag) {
    if (*flag != 1u) return;
    int n = blockIdx.x * blockDim.x + threadIdx.x;
    if (n >= N) return;
    u32 cc = cntpart[n] + cntpart[n + N];   // fields don't cross-carry
    float P = (float)(cc >> 16), Q = (float)(cc & 0xFFFFu);
    float u2 = W[4] * P + W[6] * Q;
    float z = fw[0] * fmaxf(u2, 0.0f) + fw[1] * fmaxf(-u2, 0.0f);
    out[n] = 1.0f / (1.0f + expf(-z));
}

// ---------------- partition pipeline (flag-independent) ----------------

// P0: per-(chunk,key) histogram, chunk-major H[cid][key]
__global__ __launch_bounds__(BIN_T) void hist_k(const int* __restrict__ src,
                                                const int* __restrict__ dst,
                                                int E, int gridC,
                                                u16* __restrict__ H) {
    __shared__ u32 h[NBW];
    int t = threadIdx.x;
    h[t] = 0; h[t + 1024] = 0;
    __syncthreads();
    int cid = chunk_id(blockIdx.x, gridC);
    int e0 = cid * CHUNK, e1 = min(E, e0 + CHUNK);
    for (int e = e0 + t; e < e1; e += BIN_T) {
        int key = ((dst[e] >> SB_BITS) << 3) | ((src[e] >> 17) & 7);
        atomicAdd(&h[key], 1u);
    }
    __syncthreads();
    u16* row = H + (size_t)cid * NBW;
    row[t] = (u16)h[t];
    row[t + 1024] = (u16)h[t + 1024];
}

// P1: in-place exclusive scan of H along chunks, per key; totals -> T
__global__ void colscan_k(u16* __restrict__ H, int gridC, u32* __restrict__ T) {
    __shared__ u32 tile[SCAN_BK][257];
    __shared__ u32 carry[SCAN_BK];
    int t = threadIdx.x;                // 256
    int b0 = blockIdx.x * SCAN_BK;
    if (t < SCAN_BK) carry[t] = 0;
    __syncthreads();
    int w = t >> 6, lane = t & 63;
    int rounds = (gridC + 255) / 256;
    for (int i = 0; i < rounds; ++i) {
        int blk = i * 256 + t;
        u32 vals[SCAN_BK];
        #pragma unroll
        for (int j = 0; j < SCAN_BK; ++j) vals[j] = 0;
        if (blk < gridC) {
            const u16* p = H + (size_t)blk * NBW + b0;
            uint4 v = *(const uint4*)p;     // 8 x u16
            vals[0] = v.x & 0xFFFFu; vals[1] = v.x >> 16;
            vals[2] = v.y & 0xFFFFu; vals[3] = v.y >> 16;
            vals[4] = v.z & 0xFFFFu; vals[5] = v.z >> 16;
            vals[6] = v.w & 0xFFFFu; vals[7] = v.w >> 16;
        }
        #pragma unroll
        for (int j = 0; j < SCAN_BK; ++j) tile[j][t] = vals[j];
        __syncthreads();
        for (int c = w * 2; c < w * 2 + 2; ++c) {
            u32 cb = carry[c];
            u32 run = 0;
            for (int seg = 0; seg < 4; ++seg) {
                u32 x = tile[c][seg * 64 + lane];
                u32 inc = x;
                for (int off = 1; off < 64; off <<= 1) {
                    u32 y = __shfl_up(inc, off);
                    if (lane >= off) inc += y;
                }
                tile[c][seg * 64 + lane] = inc - x + run + cb;
                run += __shfl(inc, 63);
            }
            if (lane == 0) carry[c] = cb + run;
        }
        __syncthreads();
        if (blk < gridC) {
            #pragma unroll
            for (int j = 0; j < SCAN_BK; ++j) vals[j] = tile[j][t];
            u16* p = H + (size_t)blk * NBW + b0;
            uint4 v;
            v.x = vals[0] | (vals[1] << 16);
            v.y = vals[2] | (vals[3] << 16);
            v.z = vals[4] | (vals[5] << 16);
            v.w = vals[6] | (vals[7] << 16);
            *(uint4*)p = v;
        }
        __syncthreads();
    }
    if (t < SCAN_BK) T[b0 + t] = carry[t];
}

// P2: key bases, rounded to 4 words (16B) for vectorized agg loads
__global__ __launch_bounds__(512) void base_k(const u32* __restrict__ T,
                                              u32* __restrict__ base) {
    __shared__ u32 wp[8];
    int t = threadIdx.x;                // 512, VPT = 4
    u32 loc[4];
    u32 s = 0;
    #pragma unroll
    for (int j = 0; j < 4; ++j) {
        loc[j] = (T[t * 4 + j] + 3u) & ~3u;
        s += loc[j];
    }
    int lane = t & 63, w = t >> 6;
    u32 inc = s;
    for (int off = 1; off < 64; off <<= 1) {
        u32 y = __shfl_up(inc, off);
        if (lane >= off) inc += y;
    }
    if (lane == 63) wp[w] = inc;
    __syncthreads();
    u32 add = 0;
    for (int j = 0; j < w; ++j) add += wp[j];
    u32 run = inc - s + add;
    #pragma unroll
    for (int j = 0; j < 4; ++j) {
        base[t * 4 + j] = run;
        run += loc[j];
    }
    if (t == 511) base[NBW] = run;
}

// P3: single-pass bin: per-chunk key counts derived from H prefix differences
// (count[cid][k] = H[cid+1][k] - H[cid][k]; last chunk uses T[k]).
// Block-local key sort in LDS, then coalesced run flush (~56 KB LDS).
__global__ __launch_bounds__(BIN_T) void bin_k(const int* __restrict__ src,
                                               const int* __restrict__ dst,
                                               int E, int gridC,
                                               const u16* __restrict__ H,
                                               const u32* __restrict__ T,
                                               const u32* __restrict__ base,
                                               u32* __restrict__ bucketed) {
    __shared__ u32 Dd[NBW];              // D = base + Hrow - start (mod 2^32)
    __shared__ u32 cur[NBW];
    __shared__ u32 stage[CHUNK];         // 32 KB
    __shared__ u8 sbk[CHUNK];            // 8 KB (dst bucket, < 256)
    __shared__ u32 wp[16];
    int t = threadIdx.x;                 // 1024
    int cid = chunk_id(blockIdx.x, gridC);
    int e0 = cid * CHUNK, e1 = min(E, e0 + CHUNK), n = e1 - e0;
    // this chunk's prefix row and next row (u16 pairs, one u32 load each)
    u32 pr = ((const u32*)(H + (size_t)cid * NBW))[t];
    u32 hr0 = pr & 0xFFFFu, hr1 = pr >> 16;
    u32 nr0, nr1;
    if (cid + 1 < gridC) {
        u32 nx = ((const u32*)(H + (size_t)(cid + 1) * NBW))[t];
        nr0 = nx & 0xFFFFu; nr1 = nx >> 16;
    } else {
        nr0 = T[2 * t]; nr1 = T[2 * t + 1];
    }
    u32 loc0 = nr0 - hr0, loc1 = nr1 - hr1;     // per-chunk key counts
    // exclusive scan (2 keys per thread)
    u32 s = loc0 + loc1;
    int lane = t & 63, w = t >> 6;
    u32 inc = s;
    for (int off = 1; off < 64; off <<= 1) {
        u32 y = __shfl_up(inc, off);
        if (lane >= off) inc += y;
    }
    if (lane == 63) wp[w] = inc;
    __syncthreads();
    u32 add = 0;
    for (int j = 0; j < w; ++j) add += wp[j];
    u32 run = inc - s + add;
    u32 st0 = run, st1 = run + loc0;
    cur[2 * t] = st0;
    cur[2 * t + 1] = st1;
    Dd[2 * t] = base[2 * t] + hr0 - st0;
    Dd[2 * t + 1] = base[2 * t + 1] + hr1 - st1;
    __syncthreads();
    // single edge pass: rank + stage (key-sorted within block)
    for (int e = e0 + t; e < e1; e += BIN_T) {
        int d = dst[e];
        int sc = src[e];
        int key = ((d >> SB_BITS) << 3) | ((sc >> 17) & 7);
        u32 r = atomicAdd(&cur[key], 1u);
        stage[r] = ((u32)(d & (SB - 1)) << 20) | (u32)sc;
        sbk[r] = (u8)(d >> SB_BITS);
    }
    __syncthreads();
    // flush: consecutive i -> consecutive global positions within runs
    for (int i = t; i < n; i += BIN_T) {
        u32 wv = stage[i];
        int key = ((int)sbk[i] << 3) | (int)((wv >> 17) & 7);
        bucketed[Dd[key] + (u32)i] = wv;
    }
}

// ---------------- aggregation (spec) ----------------

// agg1: f32 g-table, L2 gathers (request-rate floor). Slice-split:
// block (b,h) owns slices {h, h+2, h+4, h+6}; partials to u1part[h][N].
__global__ __launch_bounds__(1024) void agg1_s(
        const u32* __restrict__ bucketed, const u32* __restrict__ base,
        const u32* __restrict__ T, const float* __restrict__ gt,
        float* __restrict__ u1part, int N, const u32* __restrict__ flag) {
    if (*flag != 1u) return;
    __shared__ float acc[SB];            // 16 KB
    int bid = blockIdx.x, t = threadIdx.x;
    int b = bid >> 1, h = bid & 1;
    acc[t] = 0.0f; acc[t + 1024] = 0.0f;
    acc[t + 2048] = 0.0f; acc[t + 3072] = 0.0f;
    __syncthreads();
    for (int si = 0; si < 4; ++si) {
        int k = b * 8 + h + 2 * si;      // interleaved slices
        u32 p0 = base[k], cnt = T[k];
        for (u32 q = 8u * (u32)t; q < cnt; q += 8192u) {
            const u32x4* p = (const u32x4*)(bucketed + p0 + q);
            u32x4 wa = __builtin_nontemporal_load(p);
            u32x4 wb = __builtin_nontemporal_load(p + 1);
            u32 wv[8] = {wa[0], wa[1], wa[2], wa[3], wb[0], wb[1], wb[2], wb[3]};
            float gv[8];
            #pragma unroll
            for (int j = 0; j < 8; ++j) {
                u32 s = min(wv[j] & 0xFFFFFu, (u32)(N - 1));
                gv[j] = gt[s];
            }
            #pragma unroll
            for (int j = 0; j < 8; ++j)
                if (q + j < cnt)
                    atomicAdd(&acc[wv[j] >> 20], gv[j]);
        }
    }
    __syncthreads();
    int n0 = b << SB_BITS;
    float* dstp = u1part + (size_t)h * N + n0;
    for (int i = t; i < SB && n0 + i < N; i += 1024) dstp[i] = acc[i];
}

// agg2: 2-bit class table, 32 KB LDS slices (zero L2 gather requests).
// Slice-split like agg1; packed count partials to cntpart[h][N].
__global__ __launch_bounds__(1024) void agg2_s(
        const u32* __restrict__ bucketed, const u32* __restrict__ base,
        const u32* __restrict__ T, const u32* __restrict__ cls2,
        u32* __restrict__ cntpart, int N, const u32* __restrict__ flag) {
    if (*flag != 1u) return;
    __shared__ u32 acc[SB];              // 16 KB
    __shared__ u32 tbl[8192];            // 32 KB
    int bid = blockIdx.x, t = threadIdx.x;
    int b = bid >> 1, h = bid & 1;
    acc[t] = 0u; acc[t + 1024] = 0u;
    acc[t + 2048] = 0u; acc[t + 3072] = 0u;
    for (int si = 0; si < 4; ++si) {
        int sl = h + 2 * si;
        __syncthreads();                 // prev slice reads done / acc init
        #pragma unroll
        for (int j = 0; j < 8; ++j)
            tbl[t + 1024 * j] = cls2[sl * 8192 + t + 1024 * j];
        __syncthreads();
        int k = b * 8 + sl;
        u32 p0 = base[k], cnt = T[k];
        for (u32 q = 8u * (u32)t; q < cnt; q += 8192u) {
            const u32x4* p = (const u32x4*)(bucketed + p0 + q);
            u32x4 wa = __builtin_nontemporal_load(p);
            u32x4 wb = __builtin_nontemporal_load(p + 1);
            u32 wv[8] = {wa[0], wa[1], wa[2], wa[3], wb[0], wb[1], wb[2], wb[3]};
            u32 av[8];
            #pragma unroll
            for (int j = 0; j < 8; ++j) {
                u32 local = wv[j] & 0x1FFFFu;           // 17-bit in-slice id
                u32 c = (tbl[local >> 4] >> (2 * (local & 15u))) & 3u;
                av[j] = (c == 1u) ? 65536u : ((c == 2u) ? 1u : 0u);
            }
            #pragma unroll
            for (int j = 0; j < 8; ++j)
                if (q + j < cnt && av[j])
                    atomicAdd(&acc[wv[j] >> 20], av[j]);
        }
    }
    __syncthreads();
    int n0 = b << SB_BITS;
    u32* dstp = cntpart + (size_t)h * N + n0;
    for (int i = t; i < SB && n0 + i < N; i += 1024) dstp[i] = acc[i];
}

// general: float2 table -> float2 B (2 f32 LDS atomics/edge)
__global__ __launch_bounds__(1024) void agg_g(
        const u32* __restrict__ bucketed, const u32* __restrict__ base,
        const u32* __restrict__ T, const float2* __restrict__ A,
        float2* __restrict__ B, int N, const u32* __restrict__ flag) {
    if (*flag != 0u) return;
    __shared__ float acc[SB * 2];        // 32 KB
    int b = blockIdx.x, t = threadIdx.x;
    for (int i = t; i < SB * 2; i += 1024) acc[i] = 0.0f;
    __syncthreads();
    for (int sl = 0; sl < 8; ++sl) {
        int k = b * 8 + sl;
        u32 p0 = base[k], cnt = T[k];
        for (u32 q = 8u * (u32)t; q < cnt; q += 8192u) {
            const u32x4* p = (const u32x4*)(bucketed + p0 + q);
            u32x4 wa = __builtin_nontemporal_load(p);
            u32x4 wb = __builtin_nontemporal_load(p + 1);
            u32 wv[8] = {wa[0], wa[1], wa[2], wa[3], wb[0], wb[1], wb[2], wb[3]};
            float2 vv[8];
            #pragma unroll
            for (int j = 0; j < 8; ++j) {
                u32 s = min(wv[j] & 0xFFFFFu, (u32)(N - 1));
                vv[j] = A[s];
            }
            #pragma unroll
            for (int j = 0; j < 8; ++j) {
                if (q + j < cnt) {
                    int dl = (int)(wv[j] >> 20);
                    atomicAdd(&acc[2 * dl], vv[j].x);
                    atomicAdd(&acc[2 * dl + 1], vv[j].y);
                }
            }
        }
    }
    __syncthreads();
    int n0 = b << SB_BITS;
    for (int i = t; i < SB && n0 + i < N; i += 1024)
        B[n0 + i] = make_float2(acc[2 * i], acc[2 * i + 1]);
}

// ---------------- fallback: direct global-atomic scatter ----------------

__global__ void scatter_kernel(const int* __restrict__ src,
                               const int* __restrict__ dst,
                               const float2* __restrict__ A,
                               float* __restrict__ B, int E) {
    int tid = blockIdx.x * blockDim.x + threadIdx.x;
    int stride = gridDim.x * blockDim.x;
    for (int e = tid; e < E; e += stride) {
        int s = src[e];
        int d = dst[e];
        float2 v = A[s];
        atomicAdd(&B[2 * d], v.x);
        atomicAdd(&B[2 * d + 1], v.y);
    }
}

extern "C" void kernel_launch(void* const* d_in, const int* in_sizes, int n_in,
                              void* d_out, int out_size, void* d_ws, size_t ws_size,
                              hipStream_t stream) {
    const float* x = (const float*)d_in[0];          // [N,2]
    const int* edge_index = (const int*)d_in[1];     // [2,E]
    const float* W = (const float*)d_in[2];          // [2,2,2]
    const float* fw = (const float*)d_in[3];         // [2]
    float* out = (float*)d_out;                      // [N]

    const int N = in_sizes[0] / 2;
    const int E = in_sizes[1] / 2;
    const int* src = edge_index;       // row 0 = message source j
    const int* dst = edge_index + E;   // row 1 = aggregation target i

    const int NB = (N + SB - 1) >> SB_BITS;          // 245
    const int gridC = (E + CHUNK - 1) / CHUNK;       // 3907

    // workspace layout:
    //  U1 [0, 8MB): spec: g f32[N] | general: A0 float2[N]
    //  U2 [8MB, +uBytes): H u16[gridC*NBW] (dead before agg writes)
    //     spec: u1part f32[2][N] @+0 (later cntpart u32[2][N] @+0),
    //           cls2 u32[65536] @+2N*4 | general: Bg float2[N] @+0
    //  bucketed u32[E + 8192] | T u32[NBW] | base u32[NBW+1] | flag u32
    char* ws = (char*)d_ws;
    size_t aBytes = (size_t)N * 2 * sizeof(float);           // 8 MB
    size_t hBytes = (size_t)gridC * NBW * sizeof(u16);       // ~16 MB
    size_t pBytes = (size_t)N * 2 * sizeof(float) + 262144;  // partials + cls2
    size_t uBytes = hBytes > pBytes ? hBytes : pBytes;

    float* g    = (float*)ws;
    float2* A0  = (float2*)ws;
    char* U2    = ws + aBytes;
    u16*  H       = (u16*)U2;
    float* u1part = (float*)U2;                              // [2][N]
    u32*  cntpart = (u32*)U2;                                // [2][N]
    u32*  cls2    = (u32*)(U2 + (size_t)N * 2 * sizeof(float)); // 256 KB
    float* Bg     = (float*)U2;
    u32* bucketed = (u32*)(U2 + uBytes);                     // [E + 8192]
    u32* T    = bucketed + (size_t)E + 8192;                 // [NBW]
    u32* base = T + NBW;                                     // [NBW+1]
    u32* flag = base + NBW + 1;
    size_t need = (char*)(flag + 1) - ws;

    const int BLK = 256;
    const int gridN = (N + BLK - 1) / BLK;

    flag_k<<<1, 1, 0, stream>>>(W, flag);

    if (ws_size >= need && 8 * NB <= NBW && N <= (1 << 20) && E <= (1 << 25)) {
        // tables (flag-gated; disjoint use of U1)
        g_k<<<gridN, BLK, 0, stream>>>((const float2*)x, W, g, N, flag);
        norm_input_kernel<<<gridN, BLK, 0, stream>>>((const float2*)x, A0, N,
                                                     flag, 0);
        // partition (flag-independent)
        hist_k<<<gridC, BIN_T, 0, stream>>>(src, dst, E, gridC, H);
        colscan_k<<<NBW / SCAN_BK, 256, 0, stream>>>(H, gridC, T);
        base_k<<<1, 512, 0, stream>>>(T, base);
        bin_k<<<gridC, BIN_T, 0, stream>>>(src, dst, E, gridC, H, T, base,
                                           bucketed);
        // iter 1: spec f32 gathers -> u1 partials -> 2-bit classes
        agg1_s<<<2 * NB, 1024, 0, stream>>>(bucketed, base, T, g, u1part, N,
                                            flag);
        merge1_k<<<65536 / BLK, BLK, 0, stream>>>(u1part, cls2, N, flag);
        agg_g<<<NB, 1024, 0, stream>>>(bucketed, base, T, (const float2*)A0,
                                       (float2*)Bg, N, flag);
        wrelu_norm_kernel<<<gridN, BLK, 0, stream>>>((const float2*)Bg, A0, W,
                                                     N, flag, 0);
        // iter 2: spec LDS-staged 2-bit gathers -> count partials -> sigmoid
        agg2_s<<<2 * NB, 1024, 0, stream>>>(bucketed, base, T, cls2, cntpart,
                                            N, flag);
        final2_k<<<gridN, BLK, 0, stream>>>(cntpart, out, W, fw, N, flag);
        agg_g<<<NB, 1024, 0, stream>>>(bucketed, base, T, (const float2*)A0,
                                       (float2*)Bg, N, flag);
        wrelu_sig_kernel<<<gridN, BLK, 0, stream>>>((const float2*)Bg, out,
                                                    W + 4, fw, N, flag, 0);
    } else {
        // fallback: direct atomic scatter (generic, flag-independent)
        float* B = (float*)(ws + aBytes);
        const size_t featBytes = (size_t)N * 2 * sizeof(float);
        const int gridE = 8192;
        norm_input_kernel<<<gridN, BLK, 0, stream>>>((const float2*)x, A0, N,
                                                     flag, -1);
        hipMemsetAsync(B, 0, featBytes, stream);
        scatter_kernel<<<gridE, BLK, 0, stream>>>(src, dst, (const float2*)A0,
                                                  B, E);
        wrelu_norm_kernel<<<gridN, BLK, 0, stream>>>((const float2*)B, A0, W,
                                                     N, flag, -1);
        hipMemsetAsync(B, 0, featBytes, stream);
        scatter_kernel<<<gridE, BLK, 0, stream>>>(src, dst, (const float2*)A0,
                                                  B, E);
        wrelu_sig_kernel<<<gridN, BLK, 0, stream>>>((const float2*)B, out,
                                                    W + 4, fw, N, flag, -1);
    }
}

// Round 11
// 438.251 us; speedup vs baseline: 1.3934x; 1.0707x over previous
//
#include <hip/hip_runtime.h>
#include <math.h>

// 2 iterations of {row-L2-normalize -> scatter-add over 32M edges -> 2x2 matmul
// + ReLU}, then sigmoid(x @ final_weight). N = 1M nodes, E = 32M edges.
//
// Spec path (device-verified: W col1 == -col0 both iters): iter1 aggregates
// g[src] (f32 L2 gathers; pinned at the ~72 line-req/cyc device ceiling ->
// ~190us floor, confirmed R9/R10); iter2's table is ternary 2-bit (256 KB),
// 32 KB slices staged in LDS (zero L2 gather requests). Both aggs slice-split
// 2 blocks/bucket (490 blocks, 32 waves/CU). bin_k derives per-chunk key
// counts from H prefix differences (single edge pass). R11: int4-vectorized
// edge reads in hist/bin (issue-rate was the remaining non-floor overhead).

#define EPS 1e-15f
#define SB_BITS 12
#define SB 4096              // dst nodes per bucket (NB = 245)
#define NBW 2048             // padded key width (real = 245*8 = 1960)
#define CHUNK 8192           // edges per partition block
#define BIN_T 1024
#define SCAN_BK 8

typedef unsigned int u32;
typedef unsigned short u16;
typedef unsigned char u8;
typedef unsigned int u32x4 __attribute__((ext_vector_type(4)));

// XCD-contiguous chunk id: consecutive chunks land on the same XCD
__device__ inline int chunk_id(int bid, int gridC) {
    int q = gridC >> 3, r = gridC & 7;
    int x = bid & 7, i = bid >> 3;
    int base = (x < r) ? x * (q + 1) : r * (q + 1) + (x - r) * q;
    return base + i;
}

// ---------------- flag: does W have the col1 == -col0 property? ----------------

__global__ void flag_k(const float* __restrict__ W, u32* __restrict__ flag) {
    bool ok = (W[1] == -W[0]) && (W[3] == -W[2]) &&
              (W[5] == -W[4]) && (W[7] == -W[6]);
    *flag = ok ? 1u : 0u;
}

// ---------------- node-wise kernels ----------------

// spec: g[n] = (w00*x.x + w10*x.y) / (|x| + eps)
__global__ void g_k(const float2* __restrict__ x, const float* __restrict__ W,
                    float* __restrict__ g, int N, const u32* __restrict__ flag) {
    if (*flag != 1u) return;
    int n = blockIdx.x * blockDim.x + threadIdx.x;
    if (n >= N) return;
    float2 v = x[n];
    float nm = sqrtf(v.x * v.x + v.y * v.y);
    float inv = 1.0f / (nm + EPS);
    g[n] = (W[0] * v.x + W[2] * v.y) * inv;
}

// general/fallback: normalize x into A (want: -1 = always, else require *flag==want)
__global__ void norm_input_kernel(const float2* __restrict__ x,
                                  float2* __restrict__ A, int N,
                                  const u32* __restrict__ flag, int want) {
    if (want >= 0 && *flag != (u32)want) return;
    int n = blockIdx.x * blockDim.x + threadIdx.x;
    if (n >= N) return;
    float2 v = x[n];
    float nm = sqrtf(v.x * v.x + v.y * v.y);
    float inv = 1.0f / (nm + EPS);
    A[n] = make_float2(v.x * inv, v.y * inv);
}

// general/fallback: A = normalize(relu(B @ W))
__global__ void wrelu_norm_kernel(const float2* __restrict__ B,
                                  float2* __restrict__ A,
                                  const float* __restrict__ W, int N,
                                  const u32* __restrict__ flag, int want) {
    if (want >= 0 && *flag != (u32)want) return;
    int n = blockIdx.x * blockDim.x + threadIdx.x;
    if (n >= N) return;
    float w00 = W[0], w01 = W[1], w10 = W[2], w11 = W[3];
    float2 b = B[n];
    float y0 = fmaxf(b.x * w00 + b.y * w10, 0.0f);
    float y1 = fmaxf(b.x * w01 + b.y * w11, 0.0f);
    float nm = sqrtf(y0 * y0 + y1 * y1);
    float inv = 1.0f / (nm + EPS);
    A[n] = make_float2(y0 * inv, y1 * inv);
}

// general/fallback: out = sigmoid(relu(B @ W) . fw)
__global__ void wrelu_sig_kernel(const float2* __restrict__ B,
                                 float* __restrict__ out,
                                 const float* __restrict__ W,
                                 const float* __restrict__ fw, int N,
                                 const u32* __restrict__ flag, int want) {
    if (want >= 0 && *flag != (u32)want) return;
    int n = blockIdx.x * blockDim.x + threadIdx.x;
    if (n >= N) return;
    float w00 = W[0], w01 = W[1], w10 = W[2], w11 = W[3];
    float f0 = fw[0], f1 = fw[1];
    float2 b = B[n];
    float y0 = fmaxf(b.x * w00 + b.y * w10, 0.0f);
    float y1 = fmaxf(b.x * w01 + b.y * w11, 0.0f);
    float z = y0 * f0 + y1 * f1;
    out[n] = 1.0f / (1.0f + expf(-z));
}

// spec: merge u1 partials -> 2-bit class table (16 nodes/word)
__global__ void merge1_k(const float* __restrict__ u1part,
                         u32* __restrict__ cls2, int N,
                         const u32* __restrict__ flag) {
    if (*flag != 1u) return;
    int w = blockIdx.x * blockDim.x + threadIdx.x;
    if (w >= 65536) return;
    const float* p0 = u1part;
    const float* p1 = u1part + N;
    u32 word = 0;
    #pragma unroll
    for (int i = 0; i < 16; ++i) {
        int n = w * 16 + i;
        u32 c = 0;
        if (n < N) {
            float u = p0[n] + p1[n];
            c = (u > 0.0f) ? 1u : ((u < 0.0f) ? 2u : 0u);
        }
        word |= c << (2 * i);
    }
    cls2[w] = word;
}

// spec: merge packed count partials + sigmoid epilogue
__global__ void final2_k(const u32* __restrict__ cntpart,
                         float* __restrict__ out, const float* __restrict__ W,
                         const float* __restrict__ fw, int N,
                         const u32* __restrict__ flag) {
    if (*flag != 1u) return;
    int n = blockIdx.x * blockDim.x + threadIdx.x;
    if (n >= N) return;
    u32 cc = cntpart[n] + cntpart[n + N];   // fields don't cross-carry
    float P = (float)(cc >> 16), Q = (float)(cc & 0xFFFFu);
    float u2 = W[4] * P + W[6] * Q;
    float z = fw[0] * fmaxf(u2, 0.0f) + fw[1] * fmaxf(-u2, 0.0f);
    out[n] = 1.0f / (1.0f + expf(-z));
}

// ---------------- partition pipeline (flag-independent) ----------------

// P0: per-(chunk,key) histogram, chunk-major H[cid][key]; int4 edge loads
__global__ __launch_bounds__(BIN_T) void hist_k(const int* __restrict__ src,
                                                const int* __restrict__ dst,
                                                int E, int gridC,
                                                u16* __restrict__ H) {
    __shared__ u32 h[NBW];
    int t = threadIdx.x;
    h[t] = 0; h[t + 1024] = 0;
    __syncthreads();
    int cid = chunk_id(blockIdx.x, gridC);
    int e0 = cid * CHUNK, e1 = min(E, e0 + CHUNK);
    int n4 = (e1 - e0) & ~3;
    for (int e = e0 + 4 * t; e + 3 < e0 + n4; e += 4 * BIN_T) {
        int4 d4 = *(const int4*)(dst + e);
        int4 s4 = *(const int4*)(src + e);
        atomicAdd(&h[((d4.x >> SB_BITS) << 3) | ((s4.x >> 17) & 7)], 1u);
        atomicAdd(&h[((d4.y >> SB_BITS) << 3) | ((s4.y >> 17) & 7)], 1u);
        atomicAdd(&h[((d4.z >> SB_BITS) << 3) | ((s4.z >> 17) & 7)], 1u);
        atomicAdd(&h[((d4.w >> SB_BITS) << 3) | ((s4.w >> 17) & 7)], 1u);
    }
    for (int e = e0 + n4 + t; e < e1; e += BIN_T) {
        int key = ((dst[e] >> SB_BITS) << 3) | ((src[e] >> 17) & 7);
        atomicAdd(&h[key], 1u);
    }
    __syncthreads();
    u16* row = H + (size_t)cid * NBW;
    row[t] = (u16)h[t];
    row[t + 1024] = (u16)h[t + 1024];
}

// P1: in-place exclusive scan of H along chunks, per key; totals -> T
__global__ void colscan_k(u16* __restrict__ H, int gridC, u32* __restrict__ T) {
    __shared__ u32 tile[SCAN_BK][257];
    __shared__ u32 carry[SCAN_BK];
    int t = threadIdx.x;                // 256
    int b0 = blockIdx.x * SCAN_BK;
    if (t < SCAN_BK) carry[t] = 0;
    __syncthreads();
    int w = t >> 6, lane = t & 63;
    int rounds = (gridC + 255) / 256;
    for (int i = 0; i < rounds; ++i) {
        int blk = i * 256 + t;
        u32 vals[SCAN_BK];
        #pragma unroll
        for (int j = 0; j < SCAN_BK; ++j) vals[j] = 0;
        if (blk < gridC) {
            const u16* p = H + (size_t)blk * NBW + b0;
            uint4 v = *(const uint4*)p;     // 8 x u16
            vals[0] = v.x & 0xFFFFu; vals[1] = v.x >> 16;
            vals[2] = v.y & 0xFFFFu; vals[3] = v.y >> 16;
            vals[4] = v.z & 0xFFFFu; vals[5] = v.z >> 16;
            vals[6] = v.w & 0xFFFFu; vals[7] = v.w >> 16;
        }
        #pragma unroll
        for (int j = 0; j < SCAN_BK; ++j) tile[j][t] = vals[j];
        __syncthreads();
        for (int c = w * 2; c < w * 2 + 2; ++c) {
            u32 cb = carry[c];
            u32 run = 0;
            for (int seg = 0; seg < 4; ++seg) {
                u32 x = tile[c][seg * 64 + lane];
                u32 inc = x;
                for (int off = 1; off < 64; off <<= 1) {
                    u32 y = __shfl_up(inc, off);
                    if (lane >= off) inc += y;
                }
                tile[c][seg * 64 + lane] = inc - x + run + cb;
                run += __shfl(inc, 63);
            }
            if (lane == 0) carry[c] = cb + run;
        }
        __syncthreads();
        if (blk < gridC) {
            #pragma unroll
            for (int j = 0; j < SCAN_BK; ++j) vals[j] = tile[j][t];
            u16* p = H + (size_t)blk * NBW + b0;
            uint4 v;
            v.x = vals[0] | (vals[1] << 16);
            v.y = vals[2] | (vals[3] << 16);
            v.z = vals[4] | (vals[5] << 16);
            v.w = vals[6] | (vals[7] << 16);
            *(uint4*)p = v;
        }
        __syncthreads();
    }
    if (t < SCAN_BK) T[b0 + t] = carry[t];
}

// P2: key bases, rounded to 4 words (16B) for vectorized agg loads
__global__ __launch_bounds__(512) void base_k(const u32* __restrict__ T,
                                              u32* __restrict__ base) {
    __shared__ u32 wp[8];
    int t = threadIdx.x;                // 512, VPT = 4
    u32 loc[4];
    u32 s = 0;
    #pragma unroll
    for (int j = 0; j < 4; ++j) {
        loc[j] = (T[t * 4 + j] + 3u) & ~3u;
        s += loc[j];
    }
    int lane = t & 63, w = t >> 6;
    u32 inc = s;
    for (int off = 1; off < 64; off <<= 1) {
        u32 y = __shfl_up(inc, off);
        if (lane >= off) inc += y;
    }
    if (lane == 63) wp[w] = inc;
    __syncthreads();
    u32 add = 0;
    for (int j = 0; j < w; ++j) add += wp[j];
    u32 run = inc - s + add;
    #pragma unroll
    for (int j = 0; j < 4; ++j) {
        base[t * 4 + j] = run;
        run += loc[j];
    }
    if (t == 511) base[NBW] = run;
}

// P3: single-pass bin: per-chunk key counts from H prefix differences;
// int4 edge loads; block-local key sort in LDS, coalesced run flush.
__global__ __launch_bounds__(BIN_T) void bin_k(const int* __restrict__ src,
                                               const int* __restrict__ dst,
                                               int E, int gridC,
                                               const u16* __restrict__ H,
                                               const u32* __restrict__ T,
                                               const u32* __restrict__ base,
                                               u32* __restrict__ bucketed) {
    __shared__ u32 Dd[NBW];              // D = base + Hrow - start (mod 2^32)
    __shared__ u32 cur[NBW];
    __shared__ u32 stage[CHUNK];         // 32 KB
    __shared__ u8 sbk[CHUNK];            // 8 KB (dst bucket, < 256)
    __shared__ u32 wp[16];
    int t = threadIdx.x;                 // 1024
    int cid = chunk_id(blockIdx.x, gridC);
    int e0 = cid * CHUNK, e1 = min(E, e0 + CHUNK), n = e1 - e0;
    // this chunk's prefix row and next row (u16 pairs, one u32 load each)
    u32 pr = ((const u32*)(H + (size_t)cid * NBW))[t];
    u32 hr0 = pr & 0xFFFFu, hr1 = pr >> 16;
    u32 nr0, nr1;
    if (cid + 1 < gridC) {
        u32 nx = ((const u32*)(H + (size_t)(cid + 1) * NBW))[t];
        nr0 = nx & 0xFFFFu; nr1 = nx >> 16;
    } else {
        nr0 = T[2 * t]; nr1 = T[2 * t + 1];
    }
    u32 loc0 = nr0 - hr0, loc1 = nr1 - hr1;     // per-chunk key counts
    // exclusive scan (2 keys per thread)
    u32 s = loc0 + loc1;
    int lane = t & 63, w = t >> 6;
    u32 inc = s;
    for (int off = 1; off < 64; off <<= 1) {
        u32 y = __shfl_up(inc, off);
        if (lane >= off) inc += y;
    }
    if (lane == 63) wp[w] = inc;
    __syncthreads();
    u32 add = 0;
    for (int j = 0; j < w; ++j) add += wp[j];
    u32 run = inc - s + add;
    u32 st0 = run, st1 = run + loc0;
    cur[2 * t] = st0;
    cur[2 * t + 1] = st1;
    Dd[2 * t] = base[2 * t] + hr0 - st0;
    Dd[2 * t + 1] = base[2 * t + 1] + hr1 - st1;
    __syncthreads();
    // single edge pass: rank + stage (key-sorted within block), int4 loads
    int n4 = n & ~3;
    for (int e = e0 + 4 * t; e + 3 < e0 + n4; e += 4 * BIN_T) {
        int4 d4 = *(const int4*)(dst + e);
        int4 s4 = *(const int4*)(src + e);
        int dd[4] = {d4.x, d4.y, d4.z, d4.w};
        int ss[4] = {s4.x, s4.y, s4.z, s4.w};
        #pragma unroll
        for (int j = 0; j < 4; ++j) {
            int key = ((dd[j] >> SB_BITS) << 3) | ((ss[j] >> 17) & 7);
            u32 r = atomicAdd(&cur[key], 1u);
            stage[r] = ((u32)(dd[j] & (SB - 1)) << 20) | (u32)ss[j];
            sbk[r] = (u8)(dd[j] >> SB_BITS);
        }
    }
    for (int e = e0 + n4 + t; e < e1; e += BIN_T) {
        int d = dst[e];
        int sc = src[e];
        int key = ((d >> SB_BITS) << 3) | ((sc >> 17) & 7);
        u32 r = atomicAdd(&cur[key], 1u);
        stage[r] = ((u32)(d & (SB - 1)) << 20) | (u32)sc;
        sbk[r] = (u8)(d >> SB_BITS);
    }
    __syncthreads();
    // flush: consecutive i -> consecutive global positions within runs
    for (int i = t; i < n; i += BIN_T) {
        u32 wv = stage[i];
        int key = ((int)sbk[i] << 3) | (int)((wv >> 17) & 7);
        bucketed[Dd[key] + (u32)i] = wv;
    }
}

// ---------------- aggregation (spec) ----------------

// agg1: f32 g-table, L2 gathers (request-rate floor). Slice-split:
// block (b,h) owns slices {h, h+2, h+4, h+6}; partials to u1part[h][N].
__global__ __launch_bounds__(1024) void agg1_s(
        const u32* __restrict__ bucketed, const u32* __restrict__ base,
        const u32* __restrict__ T, const float* __restrict__ gt,
        float* __restrict__ u1part, int N, const u32* __restrict__ flag) {
    if (*flag != 1u) return;
    __shared__ float acc[SB];            // 16 KB
    int bid = blockIdx.x, t = threadIdx.x;
    int b = bid >> 1, h = bid & 1;
    acc[t] = 0.0f; acc[t + 1024] = 0.0f;
    acc[t + 2048] = 0.0f; acc[t + 3072] = 0.0f;
    __syncthreads();
    for (int si = 0; si < 4; ++si) {
        int k = b * 8 + h + 2 * si;      // interleaved slices
        u32 p0 = base[k], cnt = T[k];
        for (u32 q = 8u * (u32)t; q < cnt; q += 8192u) {
            const u32x4* p = (const u32x4*)(bucketed + p0 + q);
            u32x4 wa = __builtin_nontemporal_load(p);
            u32x4 wb = __builtin_nontemporal_load(p + 1);
            u32 wv[8] = {wa[0], wa[1], wa[2], wa[3], wb[0], wb[1], wb[2], wb[3]};
            float gv[8];
            #pragma unroll
            for (int j = 0; j < 8; ++j) {
                u32 s = min(wv[j] & 0xFFFFFu, (u32)(N - 1));
                gv[j] = gt[s];
            }
            #pragma unroll
            for (int j = 0; j < 8; ++j)
                if (q + j < cnt)
                    atomicAdd(&acc[wv[j] >> 20], gv[j]);
        }
    }
    __syncthreads();
    int n0 = b << SB_BITS;
    float* dstp = u1part + (size_t)h * N + n0;
    for (int i = t; i < SB && n0 + i < N; i += 1024) dstp[i] = acc[i];
}

// agg2: 2-bit class table, 32 KB LDS slices (zero L2 gather requests).
// Slice-split like agg1; packed count partials to cntpart[h][N].
__global__ __launch_bounds__(1024) void agg2_s(
        const u32* __restrict__ bucketed, const u32* __restrict__ base,
        const u32* __restrict__ T, const u32* __restrict__ cls2,
        u32* __restrict__ cntpart, int N, const u32* __restrict__ flag) {
    if (*flag != 1u) return;
    __shared__ u32 acc[SB];              // 16 KB
    __shared__ u32 tbl[8192];            // 32 KB
    int bid = blockIdx.x, t = threadIdx.x;
    int b = bid >> 1, h = bid & 1;
    acc[t] = 0u; acc[t + 1024] = 0u;
    acc[t + 2048] = 0u; acc[t + 3072] = 0u;
    for (int si = 0; si < 4; ++si) {
        int sl = h + 2 * si;
        __syncthreads();                 // prev slice reads done / acc init
        #pragma unroll
        for (int j = 0; j < 8; ++j)
            tbl[t + 1024 * j] = cls2[sl * 8192 + t + 1024 * j];
        __syncthreads();
        int k = b * 8 + sl;
        u32 p0 = base[k], cnt = T[k];
        for (u32 q = 8u * (u32)t; q < cnt; q += 8192u) {
            const u32x4* p = (const u32x4*)(bucketed + p0 + q);
            u32x4 wa = __builtin_nontemporal_load(p);
            u32x4 wb = __builtin_nontemporal_load(p + 1);
            u32 wv[8] = {wa[0], wa[1], wa[2], wa[3], wb[0], wb[1], wb[2], wb[3]};
            u32 av[8];
            #pragma unroll
            for (int j = 0; j < 8; ++j) {
                u32 local = wv[j] & 0x1FFFFu;           // 17-bit in-slice id
                u32 c = (tbl[local >> 4] >> (2 * (local & 15u))) & 3u;
                av[j] = (c == 1u) ? 65536u : ((c == 2u) ? 1u : 0u);
            }
            #pragma unroll
            for (int j = 0; j < 8; ++j)
                if (q + j < cnt && av[j])
                    atomicAdd(&acc[wv[j] >> 20], av[j]);
        }
    }
    __syncthreads();
    int n0 = b << SB_BITS;
    u32* dstp = cntpart + (size_t)h * N + n0;
    for (int i = t; i < SB && n0 + i < N; i += 1024) dstp[i] = acc[i];
}

// general: float2 table -> float2 B (2 f32 LDS atomics/edge)
__global__ __launch_bounds__(1024) void agg_g(
        const u32* __restrict__ bucketed, const u32* __restrict__ base,
        const u32* __restrict__ T, const float2* __restrict__ A,
        float2* __restrict__ B, int N, const u32* __restrict__ flag) {
    if (*flag != 0u) return;
    __shared__ float acc[SB * 2];        // 32 KB
    int b = blockIdx.x, t = threadIdx.x;
    for (int i = t; i < SB * 2; i += 1024) acc[i] = 0.0f;
    __syncthreads();
    for (int sl = 0; sl < 8; ++sl) {
        int k = b * 8 + sl;
        u32 p0 = base[k], cnt = T[k];
        for (u32 q = 8u * (u32)t; q < cnt; q += 8192u) {
            const u32x4* p = (const u32x4*)(bucketed + p0 + q);
            u32x4 wa = __builtin_nontemporal_load(p);
            u32x4 wb = __builtin_nontemporal_load(p + 1);
            u32 wv[8] = {wa[0], wa[1], wa[2], wa[3], wb[0], wb[1], wb[2], wb[3]};
            float2 vv[8];
            #pragma unroll
            for (int j = 0; j < 8; ++j) {
                u32 s = min(wv[j] & 0xFFFFFu, (u32)(N - 1));
                vv[j] = A[s];
            }
            #pragma unroll
            for (int j = 0; j < 8; ++j) {
                if (q + j < cnt) {
                    int dl = (int)(wv[j] >> 20);
                    atomicAdd(&acc[2 * dl], vv[j].x);
                    atomicAdd(&acc[2 * dl + 1], vv[j].y);
                }
            }
        }
    }
    __syncthreads();
    int n0 = b << SB_BITS;
    for (int i = t; i < SB && n0 + i < N; i += 1024)
        B[n0 + i] = make_float2(acc[2 * i], acc[2 * i + 1]);
}

// ---------------- fallback: direct global-atomic scatter ----------------

__global__ void scatter_kernel(const int* __restrict__ src,
                               const int* __restrict__ dst,
                               const float2* __restrict__ A,
                               float* __restrict__ B, int E) {
    int tid = blockIdx.x * blockDim.x + threadIdx.x;
    int stride = gridDim.x * blockDim.x;
    for (int e = tid; e < E; e += stride) {
        int s = src[e];
        int d = dst[e];
        float2 v = A[s];
        atomicAdd(&B[2 * d], v.x);
        atomicAdd(&B[2 * d + 1], v.y);
    }
}

extern "C" void kernel_launch(void* const* d_in, const int* in_sizes, int n_in,
                              void* d_out, int out_size, void* d_ws, size_t ws_size,
                              hipStream_t stream) {
    const float* x = (const float*)d_in[0];          // [N,2]
    const int* edge_index = (const int*)d_in[1];     // [2,E]
    const float* W = (const float*)d_in[2];          // [2,2,2]
    const float* fw = (const float*)d_in[3];         // [2]
    float* out = (float*)d_out;                      // [N]

    const int N = in_sizes[0] / 2;
    const int E = in_sizes[1] / 2;
    const int* src = edge_index;       // row 0 = message source j
    const int* dst = edge_index + E;   // row 1 = aggregation target i

    const int NB = (N + SB - 1) >> SB_BITS;          // 245
    const int gridC = (E + CHUNK - 1) / CHUNK;       // 3907

    // workspace layout:
    //  U1 [0, 8MB): spec: g f32[N] | general: A0 float2[N]
    //  U2 [8MB, +uBytes): H u16[gridC*NBW] (dead before agg writes)
    //     spec: u1part f32[2][N] @+0 (later cntpart u32[2][N] @+0),
    //           cls2 u32[65536] @+2N*4 | general: Bg float2[N] @+0
    //  bucketed u32[E + 8192] | T u32[NBW] | base u32[NBW+1] | flag u32
    char* ws = (char*)d_ws;
    size_t aBytes = (size_t)N * 2 * sizeof(float);           // 8 MB
    size_t hBytes = (size_t)gridC * NBW * sizeof(u16);       // ~16 MB
    size_t pBytes = (size_t)N * 2 * sizeof(float) + 262144;  // partials + cls2
    size_t uBytes = hBytes > pBytes ? hBytes : pBytes;

    float* g    = (float*)ws;
    float2* A0  = (float2*)ws;
    char* U2    = ws + aBytes;
    u16*  H       = (u16*)U2;
    float* u1part = (float*)U2;                              // [2][N]
    u32*  cntpart = (u32*)U2;                                // [2][N]
    u32*  cls2    = (u32*)(U2 + (size_t)N * 2 * sizeof(float)); // 256 KB
    float* Bg     = (float*)U2;
    u32* bucketed = (u32*)(U2 + uBytes);                     // [E + 8192]
    u32* T    = bucketed + (size_t)E + 8192;                 // [NBW]
    u32* base = T + NBW;                                     // [NBW+1]
    u32* flag = base + NBW + 1;
    size_t need = (char*)(flag + 1) - ws;

    const int BLK = 256;
    const int gridN = (N + BLK - 1) / BLK;

    flag_k<<<1, 1, 0, stream>>>(W, flag);

    if (ws_size >= need && 8 * NB <= NBW && N <= (1 << 20) && E <= (1 << 25)) {
        // tables (flag-gated; disjoint use of U1)
        g_k<<<gridN, BLK, 0, stream>>>((const float2*)x, W, g, N, flag);
        norm_input_kernel<<<gridN, BLK, 0, stream>>>((const float2*)x, A0, N,
                                                     flag, 0);
        // partition (flag-independent)
        hist_k<<<gridC, BIN_T, 0, stream>>>(src, dst, E, gridC, H);
        colscan_k<<<NBW / SCAN_BK, 256, 0, stream>>>(H, gridC, T);
        base_k<<<1, 512, 0, stream>>>(T, base);
        bin_k<<<gridC, BIN_T, 0, stream>>>(src, dst, E, gridC, H, T, base,
                                           bucketed);
        // iter 1: spec f32 gathers -> u1 partials -> 2-bit classes
        agg1_s<<<2 * NB, 1024, 0, stream>>>(bucketed, base, T, g, u1part, N,
                                            flag);
        merge1_k<<<65536 / BLK, BLK, 0, stream>>>(u1part, cls2, N, flag);
        agg_g<<<NB, 1024, 0, stream>>>(bucketed, base, T, (const float2*)A0,
                                       (float2*)Bg, N, flag);
        wrelu_norm_kernel<<<gridN, BLK, 0, stream>>>((const float2*)Bg, A0, W,
                                                     N, flag, 0);
        // iter 2: spec LDS-staged 2-bit gathers -> count partials -> sigmoid
        agg2_s<<<2 * NB, 1024, 0, stream>>>(bucketed, base, T, cls2, cntpart,
                                            N, flag);
        final2_k<<<gridN, BLK, 0, stream>>>(cntpart, out, W, fw, N, flag);
        agg_g<<<NB, 1024, 0, stream>>>(bucketed, base, T, (const float2*)A0,
                                       (float2*)Bg, N, flag);
        wrelu_sig_kernel<<<gridN, BLK, 0, stream>>>((const float2*)Bg, out,
                                                    W + 4, fw, N, flag, 0);
    } else {
        // fallback: direct atomic scatter (generic, flag-independent)
        float* B = (float*)(ws + aBytes);
        const size_t featBytes = (size_t)N * 2 * sizeof(float);
        const int gridE = 8192;
        norm_input_kernel<<<gridN, BLK, 0, stream>>>((const float2*)x, A0, N,
                                                     flag, -1);
        hipMemsetAsync(B, 0, featBytes, stream);
        scatter_kernel<<<gridE, BLK, 0, stream>>>(src, dst, (const float2*)A0,
                                                  B, E);
        wrelu_norm_kernel<<<gridN, BLK, 0, stream>>>((const float2*)B, A0, W,
                                                     N, flag, -1);
        hipMemsetAsync(B, 0, featBytes, stream);
        scatter_kernel<<<gridE, BLK, 0, stream>>>(src, dst, (const float2*)A0,
                                                  B, E);
        wrelu_sig_kernel<<<gridN, BLK, 0, stream>>>((const float2*)B, out,
                                                    W + 4, fw, N, flag, -1);
    }
}